// Round 3
// baseline (308.945 us; speedup 1.0000x reference)
//
#include <hip/hip_runtime.h>
#include <math.h>

typedef unsigned short u16;
typedef unsigned int u32;
typedef unsigned long long u64;
typedef __attribute__((ext_vector_type(8))) short short8;
typedef __attribute__((ext_vector_type(4))) float f32x4;

#define CDIM 512
#define NTOK 4096
#define MTOK 1024
#define NHEAD 8

// ---------- bf16 helpers ----------
__device__ __forceinline__ u16 f2bf(float x) {
  u32 b = __float_as_uint(x);
  u32 r = (b + 0x7FFFu + ((b >> 16) & 1u)) >> 16;
  return (u16)r;
}
__device__ __forceinline__ float bf2f(u16 u) {
  return __uint_as_float(((u32)u) << 16);
}

__device__ __forceinline__ void gload16(const void* g, void* l) {
  __builtin_amdgcn_global_load_lds(
      (const __attribute__((address_space(1))) u32*)g,
      (__attribute__((address_space(3))) u32*)l, 16, 0, 0);
}

// ---------- weight transpose+split: src [K=512][N] f32 -> dh/dl [N][512] bf16 ----------
__global__ __launch_bounds__(256) void tsplit(const float* __restrict__ src,
                                              u16* __restrict__ dh, u16* __restrict__ dl,
                                              int N) {
  int idx = blockIdx.x * 256 + threadIdx.x;  // N*512
  int n = idx >> 9, k = idx & 511;
  float v = src[(size_t)k * N + n];
  u16 hi = f2bf(v);
  dh[idx] = hi;
  dl[idx] = f2bf(v - bf2f(hi));
}

// ---------- Wsr [O=512][I=512][2][2] -> W2T [O=512][r=2048], r = p*512+i ----------
__global__ __launch_bounds__(256) void wsr_split(const float* __restrict__ Wsr,
                                                 u16* __restrict__ dh, u16* __restrict__ dl) {
  int idx = blockIdx.x * 256 + threadIdx.x;  // 512*2048
  int o = idx >> 11, r = idx & 2047;
  int p = r >> 9, i = r & 511;
  float v = Wsr[(size_t)o * 2048 + i * 4 + p];
  u16 hi = f2bf(v);
  dh[idx] = hi;
  dl[idx] = f2bf(v - bf2f(hi));
}

// ---------- generic f32 -> bf16 hi/lo split ----------
__global__ __launch_bounds__(256) void fsplit(const float* __restrict__ src,
                                              u16* __restrict__ dh, u16* __restrict__ dl) {
  int idx = blockIdx.x * 256 + threadIdx.x;
  float v = src[idx];
  u16 hi = f2bf(v);
  dh[idx] = hi;
  dl[idx] = f2bf(v - bf2f(hi));
}

// ---------- split-bf16 MFMA GEMM ----------
__global__ __launch_bounds__(256) void gemm_sp(
    const u16* __restrict__ A0h, const u16* __restrict__ A0l,
    const u16* __restrict__ A1h, const u16* __restrict__ A1l,
    const u16* __restrict__ BTh, const u16* __restrict__ BTl,
    int M, int N, int K, int kc, int nk, int mode,
    float* __restrict__ Of, u16* __restrict__ Ob,
    const float* __restrict__ bias,
    const float* __restrict__ mask0, const float* __restrict__ mask1,
    float oscale, int gather) {
  const int t = threadIdx.x;
  const int w = t >> 6;
  const int l = t & 63;
  const int lr = l & 15;
  const int lc = l >> 4;
  const int bz = blockIdx.z;
  const int br = bz / nk, kcid = bz % nk;
  const int row0 = blockIdx.y * 128;
  const int col0 = blockIdx.x * 128;
  const int koff = kcid * kc;
  const u16* Ah = br ? A1h : A0h;
  const u16* Al = br ? A1l : A0l;

  __shared__ u16 sAh[4096], sAl[4096], sBh[4096], sBl[4096];

  f32x4 acc[4][4];
#pragma unroll
  for (int a = 0; a < 4; ++a)
#pragma unroll
    for (int b = 0; b < 4; ++b) acc[a][b] = (f32x4){0.f, 0.f, 0.f, 0.f};

  for (int k0 = koff; k0 < koff + kc; k0 += 32) {
#pragma unroll
    for (int i = 0; i < 2; ++i) {
      const int f = w * 2 + i;
      const int ar = f * 16 + lr;
      size_t ga;
      if (gather) {
        const int k = k0 + lc * 8;
        const int p = k >> 9;
        const int ii = k & 511;
        const int m = row0 + ar;
        const int token = (((m >> 5) * 2 + (p >> 1)) << 6) + ((m & 31) * 2 + (p & 1));
        ga = (size_t)token * 512 + ii;
      } else {
        ga = (size_t)(row0 + ar) * K + k0 + lc * 8;
      }
      gload16(Ah + ga, (void*)&sAh[f * 512]);
      gload16(Al + ga, (void*)&sAl[f * 512]);
      const size_t gb = (size_t)(col0 + ar) * K + k0 + lc * 8;
      gload16(BTh + gb, (void*)&sBh[f * 512]);
      gload16(BTl + gb, (void*)&sBl[f * 512]);
    }
    __syncthreads();

    const int wr = (w >> 1) * 4;
    const int wc = (w & 1) * 4;
    short8 ah[4], al[4], bh[4], bl[4];
#pragma unroll
    for (int i = 0; i < 4; ++i) {
      ah[i] = *(const short8*)&sAh[(wr + i) * 512 + l * 8];
      al[i] = *(const short8*)&sAl[(wr + i) * 512 + l * 8];
      bh[i] = *(const short8*)&sBh[(wc + i) * 512 + l * 8];
      bl[i] = *(const short8*)&sBl[(wc + i) * 512 + l * 8];
    }
#pragma unroll
    for (int mt = 0; mt < 4; ++mt)
#pragma unroll
      for (int nt = 0; nt < 4; ++nt) {
        acc[mt][nt] = __builtin_amdgcn_mfma_f32_16x16x32_bf16(ah[mt], bh[nt], acc[mt][nt], 0, 0, 0);
        acc[mt][nt] = __builtin_amdgcn_mfma_f32_16x16x32_bf16(ah[mt], bl[nt], acc[mt][nt], 0, 0, 0);
        acc[mt][nt] = __builtin_amdgcn_mfma_f32_16x16x32_bf16(al[mt], bh[nt], acc[mt][nt], 0, 0, 0);
      }
    __syncthreads();
  }

  const int rowb = row0 + (w >> 1) * 64;
  const int colb = col0 + (w & 1) * 64;
  const size_t obase = (mode == 0) ? (size_t)bz * M * N : (size_t)br * M * N;
#pragma unroll
  for (int mt = 0; mt < 4; ++mt)
#pragma unroll
    for (int nt = 0; nt < 4; ++nt) {
      const int col = colb + nt * 16 + lr;
#pragma unroll
      for (int j = 0; j < 4; ++j) {
        const int row = rowb + mt * 16 + lc * 4 + j;
        float v = acc[mt][nt][j];
        if (mode == 0) {
          Of[obase + (size_t)row * N + col] = v;
        } else if (mode == 1) {
          float mv = br ? mask1[row] : mask0[row];
          Of[obase + (size_t)row * N + col] = (v + bias[col]) * mv;
        } else {
          Ob[obase + (size_t)row * N + col] = f2bf(v * oscale);
        }
      }
    }
}

// ---------- LayerNorm: sum 4 conv partials + bsr, normalize, split to bf16 hi/lo ----------
__global__ __launch_bounds__(256) void ln_split(const float* __restrict__ xr,
                                                const float* __restrict__ bsr,
                                                const float* __restrict__ gamma,
                                                const float* __restrict__ beta,
                                                u16* __restrict__ xnh, u16* __restrict__ xnl) {
  const int row = blockIdx.x;
  const int br = blockIdx.y;
  const int t = threadIdx.x;
  const float* p = xr + (size_t)br * 4 * 524288 + (size_t)row * 512;
  const int c = t * 2;
  float v0 = p[c] + p[524288 + c] + p[1048576 + c] + p[1572864 + c] + bsr[c];
  float v1 = p[c + 1] + p[524288 + c + 1] + p[1048576 + c + 1] + p[1572864 + c + 1] + bsr[c + 1];
  float s = v0 + v1, sq = v0 * v0 + v1 * v1;
#pragma unroll
  for (int m = 1; m < 64; m <<= 1) {
    s += __shfl_xor(s, m, 64);
    sq += __shfl_xor(sq, m, 64);
  }
  __shared__ float ls[4], lsq[4];
  if ((t & 63) == 0) { ls[t >> 6] = s; lsq[t >> 6] = sq; }
  __syncthreads();
  s = ls[0] + ls[1] + ls[2] + ls[3];
  sq = lsq[0] + lsq[1] + lsq[2] + lsq[3];
  float mean = s * (1.0f / 512.0f);
  float var = sq * (1.0f / 512.0f) - mean * mean;
  float rs = rsqrtf(var + 1e-5f);
  size_t ob = (size_t)br * 524288 + (size_t)row * 512 + c;
  float y0 = (v0 - mean) * rs * gamma[c] + beta[c];
  float y1 = (v1 - mean) * rs * gamma[c + 1] + beta[c + 1];
  u16 h0 = f2bf(y0), h1 = f2bf(y1);
  xnh[ob] = h0; xnh[ob + 1] = h1;
  xnl[ob] = f2bf(y0 - bf2f(h0)); xnl[ob + 1] = f2bf(y1 - bf2f(h1));
}

// ---------- V transpose: kvb [br][m][1024] -> vt [br][h][d][m] ----------
__global__ __launch_bounds__(256) void vtb(const u16* __restrict__ kvb, u16* __restrict__ vt) {
  int idx = blockIdx.x * 256 + threadIdx.x;  // 2*8*64*1024
  int m = idx & 1023;
  int rest = idx >> 10;
  int d = rest & 63;
  int h = (rest >> 6) & 7;
  int br = rest >> 9;
  vt[idx] = kvb[(size_t)br * 1048576 + (size_t)m * 1024 + 512 + h * 64 + d];
}

// ---------- MFMA flash attention, register-pipelined, no max tracking ----------
// qb [br][4096][512] bf16 (pre-scaled by 0.125*log2e), kvb [br][1024][1024],
// vt [br][8][64][1024]. Out: aoh/aol bf16 hi/lo.
__global__ __launch_bounds__(256) void attn_mfma(const u16* __restrict__ qb,
                                                 const u16* __restrict__ kvb,
                                                 const u16* __restrict__ vt,
                                                 u16* __restrict__ aoh, u16* __restrict__ aol) {
  const int t = threadIdx.x;
  const int w = t >> 6;
  const int l = t & 63;
  const int lr = l & 15;
  const int lc = l >> 4;
  const int hh = blockIdx.y;
  const int n0 = blockIdx.x * 64;
  const int br = blockIdx.z;
  qb += (size_t)br * 2097152;
  kvb += (size_t)br * 1048576;
  vt += (size_t)br * 524288;
  aoh += (size_t)br * 4194304;
  aol += (size_t)br * 4194304;

  __shared__ __align__(16) u16 Pl[4][1152];  // per-wave P: [16 q][72 kv]
  u16* Pw = &Pl[w][0];

  short8 bq[2];
  {
    const size_t qrow = (size_t)(n0 + w * 16 + lr) * 512 + hh * 64;
    bq[0] = *(const short8*)&qb[qrow + lc * 8];
    bq[1] = *(const short8*)&qb[qrow + 32 + lc * 8];
  }

  const u16* kbase = kvb + hh * 64;                  // + m*1024 + d
  const u16* vbase = vt + (size_t)hh * 64 * 1024;    // + d*1024 + m

  short8 kc[8], vc[8];
  // prologue: loads for m0 = 0
#pragma unroll
  for (int f = 0; f < 4; ++f) {
    kc[f * 2 + 0] = *(const short8*)&kbase[(size_t)(f * 16 + lr) * 1024 + lc * 8];
    kc[f * 2 + 1] = *(const short8*)&kbase[(size_t)(f * 16 + lr) * 1024 + 32 + lc * 8];
  }
#pragma unroll
  for (int ks = 0; ks < 2; ++ks)
#pragma unroll
    for (int db = 0; db < 4; ++db)
      vc[ks * 4 + db] = *(const short8*)&vbase[(size_t)(db * 16 + lr) * 1024 + ks * 32 + lc * 8];

  f32x4 acc[4];
#pragma unroll
  for (int i = 0; i < 4; ++i) acc[i] = (f32x4){0.f, 0.f, 0.f, 0.f};
  float lsum = 0.f;

  for (int it = 0; it < 16; ++it) {
    const int mn = ((it + 1) & 15) * 64;  // next tile (wraps harmlessly)

    // ---- QK^T: S^T frags [16 kv][16 q]
    f32x4 st[4];
#pragma unroll
    for (int f = 0; f < 4; ++f) {
      f32x4 s = (f32x4){0.f, 0.f, 0.f, 0.f};
      s = __builtin_amdgcn_mfma_f32_16x16x32_bf16(kc[f * 2 + 0], bq[0], s, 0, 0, 0);
      s = __builtin_amdgcn_mfma_f32_16x16x32_bf16(kc[f * 2 + 1], bq[1], s, 0, 0, 0);
      st[f] = s;
    }
    // ---- refill K for next iter (after MFMAs consumed kc; latency hides under softmax+PV)
#pragma unroll
    for (int f = 0; f < 4; ++f) {
      kc[f * 2 + 0] = *(const short8*)&kbase[(size_t)(mn + f * 16 + lr) * 1024 + lc * 8];
      kc[f * 2 + 1] = *(const short8*)&kbase[(size_t)(mn + f * 16 + lr) * 1024 + 32 + lc * 8];
    }

    // ---- softmax without max tracking: p = 2^s (scale folded into q)
#pragma unroll
    for (int f = 0; f < 4; ++f) {
      float p0, p1, p2, p3;
      asm("v_exp_f32 %0, %1" : "=v"(p0) : "v"(st[f][0]));
      asm("v_exp_f32 %0, %1" : "=v"(p1) : "v"(st[f][1]));
      asm("v_exp_f32 %0, %1" : "=v"(p2) : "v"(st[f][2]));
      asm("v_exp_f32 %0, %1" : "=v"(p3) : "v"(st[f][3]));
      lsum += (p0 + p1) + (p2 + p3);
      u32 pa, pb;
      asm("v_cvt_pk_bf16_f32 %0, %1, %2" : "=v"(pa) : "v"(p0), "v"(p1));
      asm("v_cvt_pk_bf16_f32 %0, %1, %2" : "=v"(pb) : "v"(p2), "v"(p3));
      uint2 pk; pk.x = pa; pk.y = pb;
      *(uint2*)&Pw[lr * 72 + f * 16 + lc * 4] = pk;
    }
    asm volatile("s_waitcnt lgkmcnt(0)" ::: "memory");

    // ---- PV: O^T += V^T . P^T
#pragma unroll
    for (int ks = 0; ks < 2; ++ks) {
      short8 bp = *(const short8*)&Pw[lr * 72 + ks * 32 + lc * 8];
#pragma unroll
      for (int db = 0; db < 4; ++db)
        acc[db] = __builtin_amdgcn_mfma_f32_16x16x32_bf16(vc[ks * 4 + db], bp, acc[db], 0, 0, 0);
    }
    // ---- refill V for next iter
#pragma unroll
    for (int ks = 0; ks < 2; ++ks)
#pragma unroll
      for (int db = 0; db < 4; ++db)
        vc[ks * 4 + db] = *(const short8*)&vbase[(size_t)(db * 16 + lr) * 1024 + mn + ks * 32 + lc * 8];
  }

  // ---- final softmax denominator (reduce over the 4 lanes sharing q=lr)
  lsum += __shfl_xor(lsum, 16, 64);
  lsum += __shfl_xor(lsum, 32, 64);
  const float inv = 1.0f / lsum;

  // ---- epilogue: normalize, transpose via LDS, split-write
  __shared__ float Osh[64][68];
#pragma unroll
  for (int db = 0; db < 4; ++db)
#pragma unroll
    for (int j = 0; j < 4; ++j)
      Osh[w * 16 + lr][db * 16 + lc * 4 + j] = acc[db][j] * inv;
  __syncthreads();
  const int r = t >> 2;
  const int c0 = (t & 3) * 16;
  short8 hv0, hv1, lv0, lv1;
#pragma unroll
  for (int i = 0; i < 8; ++i) {
    float v = Osh[r][c0 + i];
    u16 hi = f2bf(v);
    hv0[i] = (short)hi;
    lv0[i] = (short)f2bf(v - bf2f(hi));
  }
#pragma unroll
  for (int i = 0; i < 8; ++i) {
    float v = Osh[r][c0 + 8 + i];
    u16 hi = f2bf(v);
    hv1[i] = (short)hi;
    lv1[i] = (short)f2bf(v - bf2f(hi));
  }
  const size_t ob = (size_t)(n0 + r) * 512 + hh * 64 + c0;
  *(short8*)&aoh[ob] = hv0;
  *(short8*)&aoh[ob + 8] = hv1;
  *(short8*)&aol[ob] = lv0;
  *(short8*)&aol[ob + 8] = lv1;
}

// ---------- token exchange ----------
__global__ __launch_bounds__(256) void exchange_f32(float* __restrict__ out,
                                                    const float* __restrict__ mask0,
                                                    const float* __restrict__ mask1) {
  int idx = blockIdx.x * 256 + threadIdx.x;
  int n = idx >> 9;
  float o0 = out[idx];
  float o1 = out[idx + NTOK * CDIM];
  bool k0 = mask0[n] >= 0.02f;
  bool k1 = mask1[n] >= 0.02f;
  out[idx] = k0 ? o0 : o1;
  out[idx + NTOK * CDIM] = k1 ? o1 : o0;
}

extern "C" void kernel_launch(void* const* d_in, const int* in_sizes, int n_in,
                              void* d_out, int out_size, void* d_ws, size_t ws_size,
                              hipStream_t stream) {
  const float* x0    = (const float*)d_in[0];
  const float* x1    = (const float*)d_in[1];
  const float* mask0 = (const float*)d_in[2];
  const float* mask1 = (const float*)d_in[3];
  const float* Wq    = (const float*)d_in[4];
  const float* Wkv   = (const float*)d_in[5];
  const float* Wsr   = (const float*)d_in[6];
  const float* bsr   = (const float*)d_in[7];
  const float* gamma = (const float*)d_in[8];
  const float* beta  = (const float*)d_in[9];
  const float* Wp    = (const float*)d_in[10];
  const float* bp    = (const float*)d_in[11];

  u16* U = (u16*)d_ws;
  size_t o = 0;
  u16* WqTh = U + o; o += 262144;  u16* WqTl = U + o; o += 262144;
  u16* WkvTh = U + o; o += 524288; u16* WkvTl = U + o; o += 524288;
  u16* WpTh = U + o; o += 262144;  u16* WpTl = U + o; o += 262144;
  u16* W2Th = U + o; o += 1048576; u16* W2Tl = U + o; o += 1048576;
  u16* x0h = U + o; o += 2097152;  u16* x0l = U + o; o += 2097152;
  u16* x1h = U + o; o += 2097152;  u16* x1l = U + o; o += 2097152;
  u16* qb2 = U + o; o += 4194304;
  u16* xnh = U + o; o += 1048576;
  u16* xnl = U + o; o += 1048576;
  u16* kvb = U + o; o += 2097152;
  u16* vt  = U + o; o += 1048576;
  float* xr = (float*)(U + o);
  u16* aoh = x0h;
  u16* aol = x0l;

  float* out = (float*)d_out;
  dim3 blk(256);

  // weight prep
  tsplit<<<1024, blk, 0, stream>>>(Wq, WqTh, WqTl, 512);
  tsplit<<<2048, blk, 0, stream>>>(Wkv, WkvTh, WkvTl, 1024);
  tsplit<<<1024, blk, 0, stream>>>(Wp, WpTh, WpTl, 512);
  wsr_split<<<4096, blk, 0, stream>>>(Wsr, W2Th, W2Tl);

  // x splits
  fsplit<<<8192, blk, 0, stream>>>(x0, x0h, x0l);
  fsplit<<<8192, blk, 0, stream>>>(x1, x1h, x1l);

  // q projection -> bf16 q, pre-scaled by hd^-0.5 * log2(e)
  gemm_sp<<<dim3(4, 32, 2), blk, 0, stream>>>(x0h, x0l, x1h, x1l, WqTh, WqTl,
      4096, 512, 512, 512, 1, 2, nullptr, qb2, nullptr, nullptr, nullptr,
      0.125f * 1.4426950408889634f, 0);

  // SR conv as gather-GEMM, split-K=4 -> f32 partials
  gemm_sp<<<dim3(4, 8, 8), blk, 0, stream>>>(x0h, x0l, x1h, x1l, W2Th, W2Tl,
      1024, 512, 2048, 512, 4, 0, xr, nullptr, nullptr, nullptr, nullptr, 1.0f, 1);

  // LayerNorm (+bsr) -> split bf16
  ln_split<<<dim3(1024, 2), blk, 0, stream>>>(xr, bsr, gamma, beta, xnh, xnl);

  // kv projection -> bf16 kv
  gemm_sp<<<dim3(8, 8, 2), blk, 0, stream>>>(xnh, xnl, xnh + 524288, xnl + 524288,
      WkvTh, WkvTl, 1024, 1024, 512, 512, 1, 2, nullptr, kvb, nullptr, nullptr, nullptr, 1.0f, 0);

  // V transpose
  vtb<<<4096, blk, 0, stream>>>(kvb, vt);

  // attention -> ao hi/lo
  attn_mfma<<<dim3(64, 8, 2), blk, 0, stream>>>(qb2, kvb, vt, aoh, aol);

  // output projection + bias + mask -> f32 out
  gemm_sp<<<dim3(4, 32, 2), blk, 0, stream>>>(aoh, aol, aoh + 4194304, aol + 4194304,
      WpTh, WpTl, 4096, 512, 512, 512, 1, 1, out, nullptr, bp, mask0, mask1, 1.0f, 0);

  // token exchange
  exchange_f32<<<8192, blk, 0, stream>>>(out, mask0, mask1);
}

// Round 4
// 305.599 us; speedup vs baseline: 1.0109x; 1.0109x over previous
//
#include <hip/hip_runtime.h>
#include <math.h>

typedef unsigned short u16;
typedef unsigned int u32;
typedef unsigned long long u64;
typedef __attribute__((ext_vector_type(8))) short short8;
typedef __attribute__((ext_vector_type(4))) float f32x4;

#define CDIM 512
#define NTOK 4096
#define MTOK 1024
#define NHEAD 8

// ---------- bf16 helpers ----------
__device__ __forceinline__ u16 f2bf(float x) {
  u32 b = __float_as_uint(x);
  u32 r = (b + 0x7FFFu + ((b >> 16) & 1u)) >> 16;
  return (u16)r;
}
__device__ __forceinline__ float bf2f(u16 u) {
  return __uint_as_float(((u32)u) << 16);
}

__device__ __forceinline__ void gload16(const void* g, void* l) {
  __builtin_amdgcn_global_load_lds(
      (const __attribute__((address_space(1))) u32*)g,
      (__attribute__((address_space(3))) u32*)l, 16, 0, 0);
}

// ---------- weight transpose+split: src [K=512][N] f32 -> dh/dl [N][512] bf16 ----------
__global__ __launch_bounds__(256) void tsplit(const float* __restrict__ src,
                                              u16* __restrict__ dh, u16* __restrict__ dl,
                                              int N) {
  int idx = blockIdx.x * 256 + threadIdx.x;  // N*512
  int n = idx >> 9, k = idx & 511;
  float v = src[(size_t)k * N + n];
  u16 hi = f2bf(v);
  dh[idx] = hi;
  dl[idx] = f2bf(v - bf2f(hi));
}

// ---------- Wsr [O=512][I=512][2][2] -> W2T [O=512][r=2048], r = p*512+i ----------
__global__ __launch_bounds__(256) void wsr_split(const float* __restrict__ Wsr,
                                                 u16* __restrict__ dh, u16* __restrict__ dl) {
  int idx = blockIdx.x * 256 + threadIdx.x;  // 512*2048
  int o = idx >> 11, r = idx & 2047;
  int p = r >> 9, i = r & 511;
  float v = Wsr[(size_t)o * 2048 + i * 4 + p];
  u16 hi = f2bf(v);
  dh[idx] = hi;
  dl[idx] = f2bf(v - bf2f(hi));
}

// ---------- generic f32 -> bf16 hi/lo split ----------
__global__ __launch_bounds__(256) void fsplit(const float* __restrict__ src,
                                              u16* __restrict__ dh, u16* __restrict__ dl) {
  int idx = blockIdx.x * 256 + threadIdx.x;
  float v = src[idx];
  u16 hi = f2bf(v);
  dh[idx] = hi;
  dl[idx] = f2bf(v - bf2f(hi));
}

// ---------- split-bf16 MFMA GEMM ----------
__global__ __launch_bounds__(256) void gemm_sp(
    const u16* __restrict__ A0h, const u16* __restrict__ A0l,
    const u16* __restrict__ A1h, const u16* __restrict__ A1l,
    const u16* __restrict__ BTh, const u16* __restrict__ BTl,
    int M, int N, int K, int kc, int nk, int mode,
    float* __restrict__ Of, u16* __restrict__ Ob,
    const float* __restrict__ bias,
    const float* __restrict__ mask0, const float* __restrict__ mask1,
    float oscale, int gather) {
  const int t = threadIdx.x;
  const int w = t >> 6;
  const int l = t & 63;
  const int lr = l & 15;
  const int lc = l >> 4;
  const int bz = blockIdx.z;
  const int br = bz / nk, kcid = bz % nk;
  const int row0 = blockIdx.y * 128;
  const int col0 = blockIdx.x * 128;
  const int koff = kcid * kc;
  const u16* Ah = br ? A1h : A0h;
  const u16* Al = br ? A1l : A0l;

  __shared__ u16 sAh[4096], sAl[4096], sBh[4096], sBl[4096];

  f32x4 acc[4][4];
#pragma unroll
  for (int a = 0; a < 4; ++a)
#pragma unroll
    for (int b = 0; b < 4; ++b) acc[a][b] = (f32x4){0.f, 0.f, 0.f, 0.f};

  for (int k0 = koff; k0 < koff + kc; k0 += 32) {
#pragma unroll
    for (int i = 0; i < 2; ++i) {
      const int f = w * 2 + i;
      const int ar = f * 16 + lr;
      size_t ga;
      if (gather) {
        const int k = k0 + lc * 8;
        const int p = k >> 9;
        const int ii = k & 511;
        const int m = row0 + ar;
        const int token = (((m >> 5) * 2 + (p >> 1)) << 6) + ((m & 31) * 2 + (p & 1));
        ga = (size_t)token * 512 + ii;
      } else {
        ga = (size_t)(row0 + ar) * K + k0 + lc * 8;
      }
      gload16(Ah + ga, (void*)&sAh[f * 512]);
      gload16(Al + ga, (void*)&sAl[f * 512]);
      const size_t gb = (size_t)(col0 + ar) * K + k0 + lc * 8;
      gload16(BTh + gb, (void*)&sBh[f * 512]);
      gload16(BTl + gb, (void*)&sBl[f * 512]);
    }
    __syncthreads();

    const int wr = (w >> 1) * 4;
    const int wc = (w & 1) * 4;
    short8 ah[4], al[4], bh[4], bl[4];
#pragma unroll
    for (int i = 0; i < 4; ++i) {
      ah[i] = *(const short8*)&sAh[(wr + i) * 512 + l * 8];
      al[i] = *(const short8*)&sAl[(wr + i) * 512 + l * 8];
      bh[i] = *(const short8*)&sBh[(wc + i) * 512 + l * 8];
      bl[i] = *(const short8*)&sBl[(wc + i) * 512 + l * 8];
    }
#pragma unroll
    for (int mt = 0; mt < 4; ++mt)
#pragma unroll
      for (int nt = 0; nt < 4; ++nt) {
        acc[mt][nt] = __builtin_amdgcn_mfma_f32_16x16x32_bf16(ah[mt], bh[nt], acc[mt][nt], 0, 0, 0);
        acc[mt][nt] = __builtin_amdgcn_mfma_f32_16x16x32_bf16(ah[mt], bl[nt], acc[mt][nt], 0, 0, 0);
        acc[mt][nt] = __builtin_amdgcn_mfma_f32_16x16x32_bf16(al[mt], bh[nt], acc[mt][nt], 0, 0, 0);
      }
    __syncthreads();
  }

  const int rowb = row0 + (w >> 1) * 64;
  const int colb = col0 + (w & 1) * 64;
  const size_t obase = (mode == 0) ? (size_t)bz * M * N : (size_t)br * M * N;
#pragma unroll
  for (int mt = 0; mt < 4; ++mt)
#pragma unroll
    for (int nt = 0; nt < 4; ++nt) {
      const int col = colb + nt * 16 + lr;
#pragma unroll
      for (int j = 0; j < 4; ++j) {
        const int row = rowb + mt * 16 + lc * 4 + j;
        float v = acc[mt][nt][j];
        if (mode == 0) {
          Of[obase + (size_t)row * N + col] = v;
        } else if (mode == 1) {
          float mv = br ? mask1[row] : mask0[row];
          Of[obase + (size_t)row * N + col] = (v + bias[col]) * mv;
        } else {
          Ob[obase + (size_t)row * N + col] = f2bf(v * oscale);
        }
      }
    }
}

// ---------- LayerNorm: sum 4 conv partials + bsr, normalize, split to bf16 hi/lo ----------
__global__ __launch_bounds__(256) void ln_split(const float* __restrict__ xr,
                                                const float* __restrict__ bsr,
                                                const float* __restrict__ gamma,
                                                const float* __restrict__ beta,
                                                u16* __restrict__ xnh, u16* __restrict__ xnl) {
  const int row = blockIdx.x;
  const int br = blockIdx.y;
  const int t = threadIdx.x;
  const float* p = xr + (size_t)br * 4 * 524288 + (size_t)row * 512;
  const int c = t * 2;
  float v0 = p[c] + p[524288 + c] + p[1048576 + c] + p[1572864 + c] + bsr[c];
  float v1 = p[c + 1] + p[524288 + c + 1] + p[1048576 + c + 1] + p[1572864 + c + 1] + bsr[c + 1];
  float s = v0 + v1, sq = v0 * v0 + v1 * v1;
#pragma unroll
  for (int m = 1; m < 64; m <<= 1) {
    s += __shfl_xor(s, m, 64);
    sq += __shfl_xor(sq, m, 64);
  }
  __shared__ float ls[4], lsq[4];
  if ((t & 63) == 0) { ls[t >> 6] = s; lsq[t >> 6] = sq; }
  __syncthreads();
  s = ls[0] + ls[1] + ls[2] + ls[3];
  sq = lsq[0] + lsq[1] + lsq[2] + lsq[3];
  float mean = s * (1.0f / 512.0f);
  float var = sq * (1.0f / 512.0f) - mean * mean;
  float rs = rsqrtf(var + 1e-5f);
  size_t ob = (size_t)br * 524288 + (size_t)row * 512 + c;
  float y0 = (v0 - mean) * rs * gamma[c] + beta[c];
  float y1 = (v1 - mean) * rs * gamma[c + 1] + beta[c + 1];
  u16 h0 = f2bf(y0), h1 = f2bf(y1);
  xnh[ob] = h0; xnh[ob + 1] = h1;
  xnl[ob] = f2bf(y0 - bf2f(h0)); xnl[ob + 1] = f2bf(y1 - bf2f(h1));
}

// ---------- V transpose: kvb [br][m][1024] -> vt [br][h][d][m] ----------
__global__ __launch_bounds__(256) void vtb(const u16* __restrict__ kvb, u16* __restrict__ vt) {
  int idx = blockIdx.x * 256 + threadIdx.x;  // 2*8*64*1024
  int m = idx & 1023;
  int rest = idx >> 10;
  int d = rest & 63;
  int h = (rest >> 6) & 7;
  int br = rest >> 9;
  vt[idx] = kvb[(size_t)br * 1048576 + (size_t)m * 1024 + 512 + h * 64 + d];
}

// ---------- MFMA flash attention: 16 q per block, KV split across 4 waves ----------
// qb [br][4096][512] bf16 (pre-scaled by 0.125*log2e), kvb [br][1024][1024],
// vt [br][8][64][1024]. Out: aoh/aol bf16 hi/lo.
// Grid (256 qblk, 8 head, 2 br). Each wave: 256 kv tokens; partials add in LDS
// (valid because softmax has no max tracking: p = 2^s, sums are linear).
__global__ __launch_bounds__(256) void attn_mfma(const u16* __restrict__ qb,
                                                 const u16* __restrict__ kvb,
                                                 const u16* __restrict__ vt,
                                                 u16* __restrict__ aoh, u16* __restrict__ aol) {
  const int t = threadIdx.x;
  const int w = t >> 6;
  const int l = t & 63;
  const int lr = l & 15;
  const int lc = l >> 4;
  const int hh = blockIdx.y;
  const int n0 = blockIdx.x * 16;
  const int br = blockIdx.z;
  qb += (size_t)br * 2097152;
  kvb += (size_t)br * 1048576;
  vt += (size_t)br * 524288;
  aoh += (size_t)br * 4194304;
  aol += (size_t)br * 4194304;

  __shared__ __align__(16) u16 Pl[4][1152];   // per-wave P^T: [16 q][72 kv]
  __shared__ float Osum[4][64][17];           // per-wave O^T partial [d][q]
  __shared__ float Lsum[4][16];
  u16* Pw = &Pl[w][0];

  // Q^T B-fragments: all waves share the block's 16-q tile
  short8 bq[2];
  {
    const size_t qrow = (size_t)(n0 + lr) * 512 + hh * 64;
    bq[0] = *(const short8*)&qb[qrow + lc * 8];
    bq[1] = *(const short8*)&qb[qrow + 32 + lc * 8];
  }

  const u16* kbase = kvb + hh * 64;                  // + m*1024 + d
  const u16* vbase = vt + (size_t)hh * 64 * 1024;    // + d*1024 + m

  f32x4 acc[4];
#pragma unroll
  for (int i = 0; i < 4; ++i) acc[i] = (f32x4){0.f, 0.f, 0.f, 0.f};
  float lsum = 0.f;

  for (int it = 0; it < 4; ++it) {
    const int m0 = w * 256 + it * 64;

    // ---- QK^T: S^T frags [16 kv][16 q]
    f32x4 st[4];
    __builtin_amdgcn_s_setprio(1);
#pragma unroll
    for (int f = 0; f < 4; ++f) {
      const size_t krow = (size_t)(m0 + f * 16 + lr) * 1024;
      short8 ka = *(const short8*)&kbase[krow + lc * 8];
      short8 kb = *(const short8*)&kbase[krow + 32 + lc * 8];
      f32x4 s = (f32x4){0.f, 0.f, 0.f, 0.f};
      s = __builtin_amdgcn_mfma_f32_16x16x32_bf16(ka, bq[0], s, 0, 0, 0);
      s = __builtin_amdgcn_mfma_f32_16x16x32_bf16(kb, bq[1], s, 0, 0, 0);
      st[f] = s;
    }
    __builtin_amdgcn_s_setprio(0);

    // ---- p = 2^s (scale*log2e folded into q), pack to bf16 P^T
#pragma unroll
    for (int f = 0; f < 4; ++f) {
      float p0, p1, p2, p3;
      asm("v_exp_f32 %0, %1" : "=v"(p0) : "v"(st[f][0]));
      asm("v_exp_f32 %0, %1" : "=v"(p1) : "v"(st[f][1]));
      asm("v_exp_f32 %0, %1" : "=v"(p2) : "v"(st[f][2]));
      asm("v_exp_f32 %0, %1" : "=v"(p3) : "v"(st[f][3]));
      lsum += (p0 + p1) + (p2 + p3);
      u32 pa, pb;
      asm("v_cvt_pk_bf16_f32 %0, %1, %2" : "=v"(pa) : "v"(p0), "v"(p1));
      asm("v_cvt_pk_bf16_f32 %0, %1, %2" : "=v"(pb) : "v"(p2), "v"(p3));
      uint2 pk; pk.x = pa; pk.y = pb;
      *(uint2*)&Pw[lr * 72 + f * 16 + lc * 4] = pk;
    }

    // ---- PV: O^T += V^T . P^T  (DS pipe is in-order per wave; compiler
    // inserts the lgkmcnt for the ds_read results)
    __builtin_amdgcn_s_setprio(1);
#pragma unroll
    for (int ks = 0; ks < 2; ++ks) {
      short8 bp = *(const short8*)&Pw[lr * 72 + ks * 32 + lc * 8];
#pragma unroll
      for (int db = 0; db < 4; ++db) {
        short8 av = *(const short8*)&vbase[(size_t)(db * 16 + lr) * 1024 + m0 + ks * 32 + lc * 8];
        acc[db] = __builtin_amdgcn_mfma_f32_16x16x32_bf16(av, bp, acc[db], 0, 0, 0);
      }
    }
    __builtin_amdgcn_s_setprio(0);
  }

  // ---- per-wave partial -> LDS
  lsum += __shfl_xor(lsum, 16, 64);
  lsum += __shfl_xor(lsum, 32, 64);
#pragma unroll
  for (int db = 0; db < 4; ++db)
#pragma unroll
    for (int j = 0; j < 4; ++j)
      Osum[w][db * 16 + lc * 4 + j][lr] = acc[db][j];
  if (lc == 0) Lsum[w][lr] = lsum;
  __syncthreads();

  // ---- combine 4 wave-partials, normalize, split-write
  const int q = t & 15;
  const int d0 = (t >> 4) * 4;
  const float linv = 1.0f / (Lsum[0][q] + Lsum[1][q] + Lsum[2][q] + Lsum[3][q]);
  u64 hp = 0, lp = 0;
#pragma unroll
  for (int i = 0; i < 4; ++i) {
    const int d = d0 + i;
    float v = (Osum[0][d][q] + Osum[1][d][q] + Osum[2][d][q] + Osum[3][d][q]) * linv;
    u16 hi = f2bf(v);
    hp |= (u64)hi << (16 * i);
    lp |= (u64)f2bf(v - bf2f(hi)) << (16 * i);
  }
  const size_t ob = (size_t)(n0 + q) * 512 + hh * 64 + d0;
  *(u64*)&aoh[ob] = hp;
  *(u64*)&aol[ob] = lp;
}

// ---------- token exchange ----------
__global__ __launch_bounds__(256) void exchange_f32(float* __restrict__ out,
                                                    const float* __restrict__ mask0,
                                                    const float* __restrict__ mask1) {
  int idx = blockIdx.x * 256 + threadIdx.x;
  int n = idx >> 9;
  float o0 = out[idx];
  float o1 = out[idx + NTOK * CDIM];
  bool k0 = mask0[n] >= 0.02f;
  bool k1 = mask1[n] >= 0.02f;
  out[idx] = k0 ? o0 : o1;
  out[idx + NTOK * CDIM] = k1 ? o1 : o0;
}

extern "C" void kernel_launch(void* const* d_in, const int* in_sizes, int n_in,
                              void* d_out, int out_size, void* d_ws, size_t ws_size,
                              hipStream_t stream) {
  const float* x0    = (const float*)d_in[0];
  const float* x1    = (const float*)d_in[1];
  const float* mask0 = (const float*)d_in[2];
  const float* mask1 = (const float*)d_in[3];
  const float* Wq    = (const float*)d_in[4];
  const float* Wkv   = (const float*)d_in[5];
  const float* Wsr   = (const float*)d_in[6];
  const float* bsr   = (const float*)d_in[7];
  const float* gamma = (const float*)d_in[8];
  const float* beta  = (const float*)d_in[9];
  const float* Wp    = (const float*)d_in[10];
  const float* bp    = (const float*)d_in[11];

  u16* U = (u16*)d_ws;
  size_t o = 0;
  u16* WqTh = U + o; o += 262144;  u16* WqTl = U + o; o += 262144;
  u16* WkvTh = U + o; o += 524288; u16* WkvTl = U + o; o += 524288;
  u16* WpTh = U + o; o += 262144;  u16* WpTl = U + o; o += 262144;
  u16* W2Th = U + o; o += 1048576; u16* W2Tl = U + o; o += 1048576;
  u16* x0h = U + o; o += 2097152;  u16* x0l = U + o; o += 2097152;
  u16* x1h = U + o; o += 2097152;  u16* x1l = U + o; o += 2097152;
  u16* qb2 = U + o; o += 4194304;
  u16* xnh = U + o; o += 1048576;
  u16* xnl = U + o; o += 1048576;
  u16* kvb = U + o; o += 2097152;
  u16* vt  = U + o; o += 1048576;
  float* xr = (float*)(U + o);
  u16* aoh = x0h;   // branch stride 4194304 maps x0h->x1h, x0l->x1l
  u16* aol = x0l;

  float* out = (float*)d_out;
  dim3 blk(256);

  // weight prep
  tsplit<<<1024, blk, 0, stream>>>(Wq, WqTh, WqTl, 512);
  tsplit<<<2048, blk, 0, stream>>>(Wkv, WkvTh, WkvTl, 1024);
  tsplit<<<1024, blk, 0, stream>>>(Wp, WpTh, WpTl, 512);
  wsr_split<<<4096, blk, 0, stream>>>(Wsr, W2Th, W2Tl);

  // x splits
  fsplit<<<8192, blk, 0, stream>>>(x0, x0h, x0l);
  fsplit<<<8192, blk, 0, stream>>>(x1, x1h, x1l);

  // q projection -> bf16 q, pre-scaled by hd^-0.5 * log2(e)
  gemm_sp<<<dim3(4, 32, 2), blk, 0, stream>>>(x0h, x0l, x1h, x1l, WqTh, WqTl,
      4096, 512, 512, 512, 1, 2, nullptr, qb2, nullptr, nullptr, nullptr,
      0.125f * 1.4426950408889634f, 0);

  // SR conv as gather-GEMM, split-K=4 -> f32 partials
  gemm_sp<<<dim3(4, 8, 8), blk, 0, stream>>>(x0h, x0l, x1h, x1l, W2Th, W2Tl,
      1024, 512, 2048, 512, 4, 0, xr, nullptr, nullptr, nullptr, nullptr, 1.0f, 1);

  // LayerNorm (+bsr) -> split bf16
  ln_split<<<dim3(1024, 2), blk, 0, stream>>>(xr, bsr, gamma, beta, xnh, xnl);

  // kv projection -> bf16 kv
  gemm_sp<<<dim3(8, 8, 2), blk, 0, stream>>>(xnh, xnl, xnh + 524288, xnl + 524288,
      WkvTh, WkvTl, 1024, 1024, 512, 512, 1, 2, nullptr, kvb, nullptr, nullptr, nullptr, 1.0f, 0);

  // V transpose
  vtb<<<4096, blk, 0, stream>>>(kvb, vt);

  // attention -> ao hi/lo  (16 q per block, 4-way KV split)
  attn_mfma<<<dim3(256, 8, 2), blk, 0, stream>>>(qb2, kvb, vt, aoh, aol);

  // output projection + bias + mask -> f32 out
  gemm_sp<<<dim3(4, 32, 2), blk, 0, stream>>>(aoh, aol, aoh + 4194304, aol + 4194304,
      WpTh, WpTl, 4096, 512, 512, 512, 1, 1, out, nullptr, bp, mask0, mask1, 1.0f, 0);

  // token exchange
  exchange_f32<<<8192, blk, 0, stream>>>(out, mask0, mask1);
}

// Round 5
// 226.272 us; speedup vs baseline: 1.3654x; 1.3506x over previous
//
#include <hip/hip_runtime.h>
#include <math.h>

typedef unsigned short u16;
typedef unsigned int u32;
typedef unsigned long long u64;
typedef __attribute__((ext_vector_type(8))) short short8;
typedef __attribute__((ext_vector_type(4))) float f32x4;

#define CDIM 512
#define NTOK 4096
#define MTOK 1024
#define NHEAD 8

// ---------- bf16 helpers ----------
__device__ __forceinline__ u16 f2bf(float x) {
  u32 b = __float_as_uint(x);
  u32 r = (b + 0x7FFFu + ((b >> 16) & 1u)) >> 16;
  return (u16)r;
}
__device__ __forceinline__ float bf2f(u16 u) {
  return __uint_as_float(((u32)u) << 16);
}

__device__ __forceinline__ void gload16(const void* g, void* l) {
  __builtin_amdgcn_global_load_lds(
      (const __attribute__((address_space(1))) u32*)g,
      (__attribute__((address_space(3))) u32*)l, 16, 0, 0);
}

// ---------- weight transpose+split: src [K=512][N] f32 -> dh/dl [N][512] bf16 ----------
__global__ __launch_bounds__(256) void tsplit(const float* __restrict__ src,
                                              u16* __restrict__ dh, u16* __restrict__ dl,
                                              int N) {
  int idx = blockIdx.x * 256 + threadIdx.x;  // N*512
  int n = idx >> 9, k = idx & 511;
  float v = src[(size_t)k * N + n];
  u16 hi = f2bf(v);
  dh[idx] = hi;
  dl[idx] = f2bf(v - bf2f(hi));
}

// ---------- Wsr [O=512][I=512][2][2] -> W2T [O=512][r=2048], r = p*512+i ----------
__global__ __launch_bounds__(256) void wsr_split(const float* __restrict__ Wsr,
                                                 u16* __restrict__ dh, u16* __restrict__ dl) {
  int idx = blockIdx.x * 256 + threadIdx.x;  // 512*2048
  int o = idx >> 11, r = idx & 2047;
  int p = r >> 9, i = r & 511;
  float v = Wsr[(size_t)o * 2048 + i * 4 + p];
  u16 hi = f2bf(v);
  dh[idx] = hi;
  dl[idx] = f2bf(v - bf2f(hi));
}

// ---------- generic f32 -> bf16 hi/lo split ----------
__global__ __launch_bounds__(256) void fsplit(const float* __restrict__ src,
                                              u16* __restrict__ dh, u16* __restrict__ dl) {
  int idx = blockIdx.x * 256 + threadIdx.x;
  float v = src[idx];
  u16 hi = f2bf(v);
  dh[idx] = hi;
  dl[idx] = f2bf(v - bf2f(hi));
}

// ---------- split-bf16 MFMA GEMM ----------
__global__ __launch_bounds__(256) void gemm_sp(
    const u16* __restrict__ A0h, const u16* __restrict__ A0l,
    const u16* __restrict__ A1h, const u16* __restrict__ A1l,
    const u16* __restrict__ BTh, const u16* __restrict__ BTl,
    int M, int N, int K, int kc, int nk, int mode,
    float* __restrict__ Of, u16* __restrict__ Ob,
    const float* __restrict__ bias,
    const float* __restrict__ mask0, const float* __restrict__ mask1,
    float oscale, int gather) {
  const int t = threadIdx.x;
  const int w = t >> 6;
  const int l = t & 63;
  const int lr = l & 15;
  const int lc = l >> 4;
  const int bz = blockIdx.z;
  const int br = bz / nk, kcid = bz % nk;
  const int row0 = blockIdx.y * 128;
  const int col0 = blockIdx.x * 128;
  const int koff = kcid * kc;
  const u16* Ah = br ? A1h : A0h;
  const u16* Al = br ? A1l : A0l;

  __shared__ u16 sAh[4096], sAl[4096], sBh[4096], sBl[4096];

  f32x4 acc[4][4];
#pragma unroll
  for (int a = 0; a < 4; ++a)
#pragma unroll
    for (int b = 0; b < 4; ++b) acc[a][b] = (f32x4){0.f, 0.f, 0.f, 0.f};

  for (int k0 = koff; k0 < koff + kc; k0 += 32) {
#pragma unroll
    for (int i = 0; i < 2; ++i) {
      const int f = w * 2 + i;
      const int ar = f * 16 + lr;
      size_t ga;
      if (gather) {
        const int k = k0 + lc * 8;
        const int p = k >> 9;
        const int ii = k & 511;
        const int m = row0 + ar;
        const int token = (((m >> 5) * 2 + (p >> 1)) << 6) + ((m & 31) * 2 + (p & 1));
        ga = (size_t)token * 512 + ii;
      } else {
        ga = (size_t)(row0 + ar) * K + k0 + lc * 8;
      }
      gload16(Ah + ga, (void*)&sAh[f * 512]);
      gload16(Al + ga, (void*)&sAl[f * 512]);
      const size_t gb = (size_t)(col0 + ar) * K + k0 + lc * 8;
      gload16(BTh + gb, (void*)&sBh[f * 512]);
      gload16(BTl + gb, (void*)&sBl[f * 512]);
    }
    __syncthreads();

    const int wr = (w >> 1) * 4;
    const int wc = (w & 1) * 4;
    short8 ah[4], al[4], bh[4], bl[4];
#pragma unroll
    for (int i = 0; i < 4; ++i) {
      ah[i] = *(const short8*)&sAh[(wr + i) * 512 + l * 8];
      al[i] = *(const short8*)&sAl[(wr + i) * 512 + l * 8];
      bh[i] = *(const short8*)&sBh[(wc + i) * 512 + l * 8];
      bl[i] = *(const short8*)&sBl[(wc + i) * 512 + l * 8];
    }
#pragma unroll
    for (int mt = 0; mt < 4; ++mt)
#pragma unroll
      for (int nt = 0; nt < 4; ++nt) {
        acc[mt][nt] = __builtin_amdgcn_mfma_f32_16x16x32_bf16(ah[mt], bh[nt], acc[mt][nt], 0, 0, 0);
        acc[mt][nt] = __builtin_amdgcn_mfma_f32_16x16x32_bf16(ah[mt], bl[nt], acc[mt][nt], 0, 0, 0);
        acc[mt][nt] = __builtin_amdgcn_mfma_f32_16x16x32_bf16(al[mt], bh[nt], acc[mt][nt], 0, 0, 0);
      }
    __syncthreads();
  }

  const int rowb = row0 + (w >> 1) * 64;
  const int colb = col0 + (w & 1) * 64;
  const size_t obase = (mode == 0) ? (size_t)bz * M * N : (size_t)br * M * N;
#pragma unroll
  for (int mt = 0; mt < 4; ++mt)
#pragma unroll
    for (int nt = 0; nt < 4; ++nt) {
      const int col = colb + nt * 16 + lr;
#pragma unroll
      for (int j = 0; j < 4; ++j) {
        const int row = rowb + mt * 16 + lc * 4 + j;
        float v = acc[mt][nt][j];
        if (mode == 0) {
          Of[obase + (size_t)row * N + col] = v;
        } else if (mode == 1) {
          float mv = br ? mask1[row] : mask0[row];
          Of[obase + (size_t)row * N + col] = (v + bias[col]) * mv;
        } else {
          Ob[obase + (size_t)row * N + col] = f2bf(v * oscale);
        }
      }
    }
}

// ---------- LayerNorm: sum 4 conv partials + bsr, normalize, split to bf16 hi/lo ----------
__global__ __launch_bounds__(256) void ln_split(const float* __restrict__ xr,
                                                const float* __restrict__ bsr,
                                                const float* __restrict__ gamma,
                                                const float* __restrict__ beta,
                                                u16* __restrict__ xnh, u16* __restrict__ xnl) {
  const int row = blockIdx.x;
  const int br = blockIdx.y;
  const int t = threadIdx.x;
  const float* p = xr + (size_t)br * 4 * 524288 + (size_t)row * 512;
  const int c = t * 2;
  float v0 = p[c] + p[524288 + c] + p[1048576 + c] + p[1572864 + c] + bsr[c];
  float v1 = p[c + 1] + p[524288 + c + 1] + p[1048576 + c + 1] + p[1572864 + c + 1] + bsr[c + 1];
  float s = v0 + v1, sq = v0 * v0 + v1 * v1;
#pragma unroll
  for (int m = 1; m < 64; m <<= 1) {
    s += __shfl_xor(s, m, 64);
    sq += __shfl_xor(sq, m, 64);
  }
  __shared__ float ls[4], lsq[4];
  if ((t & 63) == 0) { ls[t >> 6] = s; lsq[t >> 6] = sq; }
  __syncthreads();
  s = ls[0] + ls[1] + ls[2] + ls[3];
  sq = lsq[0] + lsq[1] + lsq[2] + lsq[3];
  float mean = s * (1.0f / 512.0f);
  float var = sq * (1.0f / 512.0f) - mean * mean;
  float rs = rsqrtf(var + 1e-5f);
  size_t ob = (size_t)br * 524288 + (size_t)row * 512 + c;
  float y0 = (v0 - mean) * rs * gamma[c] + beta[c];
  float y1 = (v1 - mean) * rs * gamma[c + 1] + beta[c + 1];
  u16 h0 = f2bf(y0), h1 = f2bf(y1);
  xnh[ob] = h0; xnh[ob + 1] = h1;
  xnl[ob] = f2bf(y0 - bf2f(h0)); xnl[ob + 1] = f2bf(y1 - bf2f(h1));
}

// ---------- pack K and V^T into MFMA A-fragment layout ----------
// kf: [br][h][mt16=64][kt=2] frag of 64 lanes x 8 u16  (K rows 16 x k 32)
//     element: K[mt16*16 + (l&15)][kt*32 + (l>>4)*8 + j]
// vf: [br][h][m32=32][dt=4] frag (V^T rows d 16 x m 32)
//     element: V[m32*32 + (l>>4)*8 + j][dt*16 + (l&15)]
__global__ __launch_bounds__(256) void kvpack(const u16* __restrict__ kvb,
                                              u16* __restrict__ kf, u16* __restrict__ vf) {
  const int tg = blockIdx.x * 256 + threadIdx.x;   // 2^18 threads
  const int l = tg & 63;
  const int frag = (tg >> 6) & 127;
  const int h = (tg >> 13) & 7;
  const int br = (tg >> 16) & 1;
  const int which = tg >> 17;
  const int lr = l & 15;
  const int lq = l >> 4;
  const size_t dst = (size_t)br * 524288 + (size_t)h * 65536 + (size_t)frag * 512 + l * 8;
  if (which == 0) {
    const int m = (frag >> 1) * 16 + lr;
    const int d = (frag & 1) * 32 + lq * 8;
    short8 v = *(const short8*)&kvb[(size_t)br * 1048576 + (size_t)m * 1024 + h * 64 + d];
    *(short8*)&kf[dst] = v;
  } else {
    const int m = (frag >> 2) * 32 + lq * 8;
    const int d = (frag & 3) * 16 + lr;
    const u16* src = &kvb[(size_t)br * 1048576 + (size_t)m * 1024 + 512 + h * 64 + d];
    short8 v;
#pragma unroll
    for (int j = 0; j < 8; ++j) v[j] = (short)src[(size_t)j * 1024];
    *(short8*)&vf[dst] = v;
  }
}

// ---------- MFMA flash attention: fragment-layout K/V, 16 q per block ----------
// qb [br][4096][512] bf16 (pre-scaled by 0.125*log2e), kf/vf fragment-packed.
// Grid (256 qblk, 8 head, 2 br); wave w handles kv tokens [w*256, w*256+256);
// partials (no max tracking -> linear) combine in LDS.
__global__ __launch_bounds__(256) void attn_mfma(const u16* __restrict__ qb,
                                                 const u16* __restrict__ kf,
                                                 const u16* __restrict__ vf,
                                                 u16* __restrict__ aoh, u16* __restrict__ aol) {
  const int t = threadIdx.x;
  const int w = t >> 6;
  const int l = t & 63;
  const int lr = l & 15;
  const int lc = l >> 4;
  const int hh = blockIdx.y;
  const int n0 = blockIdx.x * 16;
  const int br = blockIdx.z;
  qb += (size_t)br * 2097152;
  kf += (size_t)br * 524288 + (size_t)hh * 65536;
  vf += (size_t)br * 524288 + (size_t)hh * 65536;
  aoh += (size_t)br * 4194304;
  aol += (size_t)br * 4194304;

  __shared__ __align__(16) u16 Pl[4][1152];   // per-wave P^T: [16 q][72 kv]
  __shared__ float Osum[4][64][17];           // per-wave O^T partial [d][q]
  __shared__ float Lsum[4][16];
  u16* Pw = &Pl[w][0];

  // Q^T B-fragments: all waves share the block's 16-q tile
  short8 bq[2];
  {
    const size_t qrow = (size_t)(n0 + lr) * 512 + hh * 64;
    bq[0] = *(const short8*)&qb[qrow + lc * 8];
    bq[1] = *(const short8*)&qb[qrow + 32 + lc * 8];
  }

  f32x4 acc[4];
#pragma unroll
  for (int i = 0; i < 4; ++i) acc[i] = (f32x4){0.f, 0.f, 0.f, 0.f};
  float lsum = 0.f;

  for (int it = 0; it < 4; ++it) {
    const int m0 = w * 256 + it * 64;

    // ---- load 8 K frags (contiguous 1024 B each), then QK^T
    const u16* ktile = kf + (size_t)(m0 >> 4) * 1024;
    short8 kc[8];
#pragma unroll
    for (int f = 0; f < 8; ++f)
      kc[f] = *(const short8*)&ktile[(size_t)f * 512 + l * 8];

    f32x4 st[4];
    __builtin_amdgcn_s_setprio(1);
#pragma unroll
    for (int f = 0; f < 4; ++f) {
      f32x4 s = (f32x4){0.f, 0.f, 0.f, 0.f};
      s = __builtin_amdgcn_mfma_f32_16x16x32_bf16(kc[f * 2 + 0], bq[0], s, 0, 0, 0);
      s = __builtin_amdgcn_mfma_f32_16x16x32_bf16(kc[f * 2 + 1], bq[1], s, 0, 0, 0);
      st[f] = s;
    }
    __builtin_amdgcn_s_setprio(0);

    // ---- load 8 V^T frags for this tile (contiguous), overlap with softmax
    const u16* vtile = vf + (size_t)(m0 >> 5) * 2048;
    short8 av[8];
#pragma unroll
    for (int f = 0; f < 8; ++f)
      av[f] = *(const short8*)&vtile[(size_t)f * 512 + l * 8];

    // ---- p = 2^s (scale*log2e folded into q), pack to bf16 P^T
#pragma unroll
    for (int f = 0; f < 4; ++f) {
      float p0, p1, p2, p3;
      asm("v_exp_f32 %0, %1" : "=v"(p0) : "v"(st[f][0]));
      asm("v_exp_f32 %0, %1" : "=v"(p1) : "v"(st[f][1]));
      asm("v_exp_f32 %0, %1" : "=v"(p2) : "v"(st[f][2]));
      asm("v_exp_f32 %0, %1" : "=v"(p3) : "v"(st[f][3]));
      lsum += (p0 + p1) + (p2 + p3);
      u32 pa, pb;
      asm("v_cvt_pk_bf16_f32 %0, %1, %2" : "=v"(pa) : "v"(p0), "v"(p1));
      asm("v_cvt_pk_bf16_f32 %0, %1, %2" : "=v"(pb) : "v"(p2), "v"(p3));
      uint2 pk; pk.x = pa; pk.y = pb;
      *(uint2*)&Pw[lr * 72 + f * 16 + lc * 4] = pk;
    }

    // ---- PV: O^T += V^T . P^T   (frag f = ks*4+db: ks m-half, db d-block)
    __builtin_amdgcn_s_setprio(1);
#pragma unroll
    for (int ks = 0; ks < 2; ++ks) {
      short8 bp = *(const short8*)&Pw[lr * 72 + ks * 32 + lc * 8];
#pragma unroll
      for (int db = 0; db < 4; ++db)
        acc[db] = __builtin_amdgcn_mfma_f32_16x16x32_bf16(av[ks * 4 + db], bp, acc[db], 0, 0, 0);
    }
    __builtin_amdgcn_s_setprio(0);
  }

  // ---- per-wave partial -> LDS
  lsum += __shfl_xor(lsum, 16, 64);
  lsum += __shfl_xor(lsum, 32, 64);
#pragma unroll
  for (int db = 0; db < 4; ++db)
#pragma unroll
    for (int j = 0; j < 4; ++j)
      Osum[w][db * 16 + lc * 4 + j][lr] = acc[db][j];
  if (lc == 0) Lsum[w][lr] = lsum;
  __syncthreads();

  // ---- combine 4 wave-partials, normalize, split-write
  const int q = t & 15;
  const int d0 = (t >> 4) * 4;
  const float linv = 1.0f / (Lsum[0][q] + Lsum[1][q] + Lsum[2][q] + Lsum[3][q]);
  u64 hp = 0, lp = 0;
#pragma unroll
  for (int i = 0; i < 4; ++i) {
    const int d = d0 + i;
    float v = (Osum[0][d][q] + Osum[1][d][q] + Osum[2][d][q] + Osum[3][d][q]) * linv;
    u16 hi = f2bf(v);
    hp |= (u64)hi << (16 * i);
    lp |= (u64)f2bf(v - bf2f(hi)) << (16 * i);
  }
  const size_t ob = (size_t)(n0 + q) * 512 + hh * 64 + d0;
  *(u64*)&aoh[ob] = hp;
  *(u64*)&aol[ob] = lp;
}

// ---------- token exchange ----------
__global__ __launch_bounds__(256) void exchange_f32(float* __restrict__ out,
                                                    const float* __restrict__ mask0,
                                                    const float* __restrict__ mask1) {
  int idx = blockIdx.x * 256 + threadIdx.x;
  int n = idx >> 9;
  float o0 = out[idx];
  float o1 = out[idx + NTOK * CDIM];
  bool k0 = mask0[n] >= 0.02f;
  bool k1 = mask1[n] >= 0.02f;
  out[idx] = k0 ? o0 : o1;
  out[idx + NTOK * CDIM] = k1 ? o1 : o0;
}

extern "C" void kernel_launch(void* const* d_in, const int* in_sizes, int n_in,
                              void* d_out, int out_size, void* d_ws, size_t ws_size,
                              hipStream_t stream) {
  const float* x0    = (const float*)d_in[0];
  const float* x1    = (const float*)d_in[1];
  const float* mask0 = (const float*)d_in[2];
  const float* mask1 = (const float*)d_in[3];
  const float* Wq    = (const float*)d_in[4];
  const float* Wkv   = (const float*)d_in[5];
  const float* Wsr   = (const float*)d_in[6];
  const float* bsr   = (const float*)d_in[7];
  const float* gamma = (const float*)d_in[8];
  const float* beta  = (const float*)d_in[9];
  const float* Wp    = (const float*)d_in[10];
  const float* bp    = (const float*)d_in[11];

  u16* U = (u16*)d_ws;
  size_t o = 0;
  u16* WqTh = U + o; o += 262144;  u16* WqTl = U + o; o += 262144;
  u16* WkvTh = U + o; o += 524288; u16* WkvTl = U + o; o += 524288;
  u16* WpTh = U + o; o += 262144;  u16* WpTl = U + o; o += 262144;
  u16* W2Th = U + o; o += 1048576; u16* W2Tl = U + o; o += 1048576;
  u16* x0h = U + o; o += 2097152;  u16* x0l = U + o; o += 2097152;
  u16* x1h = U + o; o += 2097152;  u16* x1l = U + o; o += 2097152;
  u16* qb2 = U + o; o += 4194304;
  u16* xnh = U + o; o += 1048576;
  u16* xnl = U + o; o += 1048576;
  u16* kvb = U + o; o += 2097152;
  u16* vt  = U + o; o += 1048576;   // (unused now, kept for layout stability)
  float* xr = (float*)(U + o);      // conv partials; dead after ln_split
  // kf/vf reuse the xr region (dead by the time kvpack runs)
  u16* kf = (u16*)xr;               // 2 br x 524288
  u16* vf = kf + 1048576;           // 2 br x 524288
  u16* aoh = x0h;   // branch stride 4194304 maps x0h->x1h, x0l->x1l
  u16* aol = x0l;

  float* out = (float*)d_out;
  dim3 blk(256);

  // weight prep
  tsplit<<<1024, blk, 0, stream>>>(Wq, WqTh, WqTl, 512);
  tsplit<<<2048, blk, 0, stream>>>(Wkv, WkvTh, WkvTl, 1024);
  tsplit<<<1024, blk, 0, stream>>>(Wp, WpTh, WpTl, 512);
  wsr_split<<<4096, blk, 0, stream>>>(Wsr, W2Th, W2Tl);

  // x splits
  fsplit<<<8192, blk, 0, stream>>>(x0, x0h, x0l);
  fsplit<<<8192, blk, 0, stream>>>(x1, x1h, x1l);

  // q projection -> bf16 q, pre-scaled by hd^-0.5 * log2(e)
  gemm_sp<<<dim3(4, 32, 2), blk, 0, stream>>>(x0h, x0l, x1h, x1l, WqTh, WqTl,
      4096, 512, 512, 512, 1, 2, nullptr, qb2, nullptr, nullptr, nullptr,
      0.125f * 1.4426950408889634f, 0);

  // SR conv as gather-GEMM, split-K=4 -> f32 partials
  gemm_sp<<<dim3(4, 8, 8), blk, 0, stream>>>(x0h, x0l, x1h, x1l, W2Th, W2Tl,
      1024, 512, 2048, 512, 4, 0, xr, nullptr, nullptr, nullptr, nullptr, 1.0f, 1);

  // LayerNorm (+bsr) -> split bf16
  ln_split<<<dim3(1024, 2), blk, 0, stream>>>(xr, bsr, gamma, beta, xnh, xnl);

  // kv projection -> bf16 kv
  gemm_sp<<<dim3(8, 8, 2), blk, 0, stream>>>(xnh, xnl, xnh + 524288, xnl + 524288,
      WkvTh, WkvTl, 1024, 1024, 512, 512, 1, 2, nullptr, kvb, nullptr, nullptr, nullptr, 1.0f, 0);

  // pack K and V^T into MFMA fragment layout
  kvpack<<<1024, blk, 0, stream>>>(kvb, kf, vf);

  // attention -> ao hi/lo  (16 q per block, 4-way KV split, fragment loads)
  attn_mfma<<<dim3(256, 8, 2), blk, 0, stream>>>(qb2, kf, vf, aoh, aol);

  // output projection + bias + mask -> f32 out
  gemm_sp<<<dim3(4, 32, 2), blk, 0, stream>>>(aoh, aol, aoh + 4194304, aol + 4194304,
      WpTh, WpTl, 4096, 512, 512, 512, 1, 1, out, nullptr, bp, mask0, mask1, 1.0f, 0);

  // token exchange
  exchange_f32<<<8192, blk, 0, stream>>>(out, mask0, mask1);
}

// Round 6
// 202.514 us; speedup vs baseline: 1.5256x; 1.1173x over previous
//
#include <hip/hip_runtime.h>
#include <math.h>

typedef unsigned short u16;
typedef unsigned int u32;
typedef unsigned long long u64;
typedef __attribute__((ext_vector_type(8))) short short8;
typedef __attribute__((ext_vector_type(4))) float f32x4;

#define CDIM 512
#define NTOK 4096
#define MTOK 1024
#define NHEAD 8

// ---------- bf16 helpers ----------
__device__ __forceinline__ u16 f2bf(float x) {
  u32 b = __float_as_uint(x);
  u32 r = (b + 0x7FFFu + ((b >> 16) & 1u)) >> 16;
  return (u16)r;
}
__device__ __forceinline__ float bf2f(u16 u) {
  return __uint_as_float(((u32)u) << 16);
}

__device__ __forceinline__ void gload16(const void* g, void* l) {
  __builtin_amdgcn_global_load_lds(
      (const __attribute__((address_space(1))) u32*)g,
      (__attribute__((address_space(3))) u32*)l, 16, 0, 0);
}

// ---------- weight transpose+split: src [K=512][N] f32 -> dh/dl [N][512] bf16 ----------
__global__ __launch_bounds__(256) void tsplit(const float* __restrict__ src,
                                              u16* __restrict__ dh, u16* __restrict__ dl,
                                              int N) {
  int idx = blockIdx.x * 256 + threadIdx.x;  // N*512
  int n = idx >> 9, k = idx & 511;
  float v = src[(size_t)k * N + n];
  u16 hi = f2bf(v);
  dh[idx] = hi;
  dl[idx] = f2bf(v - bf2f(hi));
}

// ---------- Wsr [O=512][I=512][2][2] -> W2T [O=512][r=2048], r = p*512+i ----------
__global__ __launch_bounds__(256) void wsr_split(const float* __restrict__ Wsr,
                                                 u16* __restrict__ dh, u16* __restrict__ dl) {
  int idx = blockIdx.x * 256 + threadIdx.x;  // 512*2048
  int o = idx >> 11, r = idx & 2047;
  int p = r >> 9, i = r & 511;
  float v = Wsr[(size_t)o * 2048 + i * 4 + p];
  u16 hi = f2bf(v);
  dh[idx] = hi;
  dl[idx] = f2bf(v - bf2f(hi));
}

// ---------- generic f32 -> bf16 hi/lo split ----------
__global__ __launch_bounds__(256) void fsplit(const float* __restrict__ src,
                                              u16* __restrict__ dh, u16* __restrict__ dl) {
  int idx = blockIdx.x * 256 + threadIdx.x;
  float v = src[idx];
  u16 hi = f2bf(v);
  dh[idx] = hi;
  dl[idx] = f2bf(v - bf2f(hi));
}

// ---------- split-bf16 MFMA GEMM, 64x64 tile (high-occupancy for skinny N) ----------
// A (per branch): [M][K] bf16 hi/lo (or gather from x for conv). BT: [N][K] hi/lo.
// modes: 0 = f32 at Of + bz*M*N; 1 = f32 (+bias)*mask at Of + br*M*N;
//        2 = bf16(acc*oscale) at Ob + br*M*N.
__global__ __launch_bounds__(256) void gemm_sp(
    const u16* __restrict__ A0h, const u16* __restrict__ A0l,
    const u16* __restrict__ A1h, const u16* __restrict__ A1l,
    const u16* __restrict__ BTh, const u16* __restrict__ BTl,
    int M, int N, int K, int kc, int nk, int mode,
    float* __restrict__ Of, u16* __restrict__ Ob,
    const float* __restrict__ bias,
    const float* __restrict__ mask0, const float* __restrict__ mask1,
    float oscale, int gather) {
  const int t = threadIdx.x;
  const int w = t >> 6;
  const int l = t & 63;
  const int lr = l & 15;
  const int lc = l >> 4;
  const int bz = blockIdx.z;
  const int br = bz / nk, kcid = bz % nk;
  const int row0 = blockIdx.y * 64;
  const int col0 = blockIdx.x * 64;
  const int koff = kcid * kc;
  const u16* Ah = br ? A1h : A0h;
  const u16* Al = br ? A1l : A0l;

  // fragment-major: 4 frags x 512 u16 per array
  __shared__ u16 sAh[2048], sAl[2048], sBh[2048], sBl[2048];

  f32x4 acc[2][2];
#pragma unroll
  for (int a = 0; a < 2; ++a)
#pragma unroll
    for (int b = 0; b < 2; ++b) acc[a][b] = (f32x4){0.f, 0.f, 0.f, 0.f};

  for (int k0 = koff; k0 < koff + kc; k0 += 32) {
    // wave w stages frag w of each of the 4 tiles (1 KB each)
    {
      const int ar = w * 16 + lr;
      size_t ga;
      if (gather) {
        const int k = k0 + lc * 8;
        const int p = k >> 9;
        const int ii = k & 511;
        const int m = row0 + ar;
        const int token = (((m >> 5) * 2 + (p >> 1)) << 6) + ((m & 31) * 2 + (p & 1));
        ga = (size_t)token * 512 + ii;
      } else {
        ga = (size_t)(row0 + ar) * K + k0 + lc * 8;
      }
      gload16(Ah + ga, (void*)&sAh[w * 512]);
      gload16(Al + ga, (void*)&sAl[w * 512]);
      const size_t gb = (size_t)(col0 + ar) * K + k0 + lc * 8;
      gload16(BTh + gb, (void*)&sBh[w * 512]);
      gload16(BTl + gb, (void*)&sBl[w * 512]);
    }
    __syncthreads();

    const int wr = (w >> 1) * 2;
    const int wc = (w & 1) * 2;
    short8 ah[2], al[2], bh[2], bl[2];
#pragma unroll
    for (int i = 0; i < 2; ++i) {
      ah[i] = *(const short8*)&sAh[(wr + i) * 512 + l * 8];
      al[i] = *(const short8*)&sAl[(wr + i) * 512 + l * 8];
      bh[i] = *(const short8*)&sBh[(wc + i) * 512 + l * 8];
      bl[i] = *(const short8*)&sBl[(wc + i) * 512 + l * 8];
    }
#pragma unroll
    for (int mt = 0; mt < 2; ++mt)
#pragma unroll
      for (int nt = 0; nt < 2; ++nt) {
        acc[mt][nt] = __builtin_amdgcn_mfma_f32_16x16x32_bf16(ah[mt], bh[nt], acc[mt][nt], 0, 0, 0);
        acc[mt][nt] = __builtin_amdgcn_mfma_f32_16x16x32_bf16(ah[mt], bl[nt], acc[mt][nt], 0, 0, 0);
        acc[mt][nt] = __builtin_amdgcn_mfma_f32_16x16x32_bf16(al[mt], bh[nt], acc[mt][nt], 0, 0, 0);
      }
    __syncthreads();
  }

  const int rowb = row0 + (w >> 1) * 32;
  const int colb = col0 + (w & 1) * 32;
  const size_t obase = (mode == 0) ? (size_t)bz * M * N : (size_t)br * M * N;
#pragma unroll
  for (int mt = 0; mt < 2; ++mt)
#pragma unroll
    for (int nt = 0; nt < 2; ++nt) {
      const int col = colb + nt * 16 + lr;
#pragma unroll
      for (int j = 0; j < 4; ++j) {
        const int row = rowb + mt * 16 + lc * 4 + j;
        float v = acc[mt][nt][j];
        if (mode == 0) {
          Of[obase + (size_t)row * N + col] = v;
        } else if (mode == 1) {
          float mv = br ? mask1[row] : mask0[row];
          Of[obase + (size_t)row * N + col] = (v + bias[col]) * mv;
        } else {
          Ob[obase + (size_t)row * N + col] = f2bf(v * oscale);
        }
      }
    }
}

// ---------- LayerNorm: sum 2 conv partials + bsr, normalize, split to bf16 hi/lo ----------
__global__ __launch_bounds__(256) void ln_split(const float* __restrict__ xr,
                                                const float* __restrict__ bsr,
                                                const float* __restrict__ gamma,
                                                const float* __restrict__ beta,
                                                u16* __restrict__ xnh, u16* __restrict__ xnl) {
  const int row = blockIdx.x;
  const int br = blockIdx.y;
  const int t = threadIdx.x;
  const float* p = xr + (size_t)br * 2 * 524288 + (size_t)row * 512;
  const int c = t * 2;
  float v0 = p[c] + p[524288 + c] + bsr[c];
  float v1 = p[c + 1] + p[524288 + c + 1] + bsr[c + 1];
  float s = v0 + v1, sq = v0 * v0 + v1 * v1;
#pragma unroll
  for (int m = 1; m < 64; m <<= 1) {
    s += __shfl_xor(s, m, 64);
    sq += __shfl_xor(sq, m, 64);
  }
  __shared__ float ls[4], lsq[4];
  if ((t & 63) == 0) { ls[t >> 6] = s; lsq[t >> 6] = sq; }
  __syncthreads();
  s = ls[0] + ls[1] + ls[2] + ls[3];
  sq = lsq[0] + lsq[1] + lsq[2] + lsq[3];
  float mean = s * (1.0f / 512.0f);
  float var = sq * (1.0f / 512.0f) - mean * mean;
  float rs = rsqrtf(var + 1e-5f);
  size_t ob = (size_t)br * 524288 + (size_t)row * 512 + c;
  float y0 = (v0 - mean) * rs * gamma[c] + beta[c];
  float y1 = (v1 - mean) * rs * gamma[c + 1] + beta[c + 1];
  u16 h0 = f2bf(y0), h1 = f2bf(y1);
  xnh[ob] = h0; xnh[ob + 1] = h1;
  xnl[ob] = f2bf(y0 - bf2f(h0)); xnl[ob + 1] = f2bf(y1 - bf2f(h1));
}

// ---------- pack K and V^T into MFMA A-fragment layout ----------
// kf: [br][h][mt16=64][kt=2] frag of 64 lanes x 8 u16  (K rows 16 x k 32)
// vf: [br][h][m32=32][dt=4] frag (V^T rows d 16 x m 32)
__global__ __launch_bounds__(256) void kvpack(const u16* __restrict__ kvb,
                                              u16* __restrict__ kf, u16* __restrict__ vf) {
  const int tg = blockIdx.x * 256 + threadIdx.x;   // 2^18 threads
  const int l = tg & 63;
  const int frag = (tg >> 6) & 127;
  const int h = (tg >> 13) & 7;
  const int br = (tg >> 16) & 1;
  const int which = tg >> 17;
  const int lr = l & 15;
  const int lq = l >> 4;
  const size_t dst = (size_t)br * 524288 + (size_t)h * 65536 + (size_t)frag * 512 + l * 8;
  if (which == 0) {
    const int m = (frag >> 1) * 16 + lr;
    const int d = (frag & 1) * 32 + lq * 8;
    short8 v = *(const short8*)&kvb[(size_t)br * 1048576 + (size_t)m * 1024 + h * 64 + d];
    *(short8*)&kf[dst] = v;
  } else {
    const int m = (frag >> 2) * 32 + lq * 8;
    const int d = (frag & 3) * 16 + lr;
    const u16* src = &kvb[(size_t)br * 1048576 + (size_t)m * 1024 + 512 + h * 64 + d];
    short8 v;
#pragma unroll
    for (int j = 0; j < 8; ++j) v[j] = (short)src[(size_t)j * 1024];
    *(short8*)&vf[dst] = v;
  }
}

// ---------- MFMA flash attention: fragment K/V, 32 q per block, 4-way KV split ----------
// qb [br][4096][512] bf16 (pre-scaled by 0.125*log2e), kf/vf fragment-packed.
// Grid (128 qblk, 8 head, 2 br); wave w handles kv [w*256, w*256+256);
// partials (no max tracking -> linear) combine in LDS.
__global__ __launch_bounds__(256) void attn_mfma(const u16* __restrict__ qb,
                                                 const u16* __restrict__ kf,
                                                 const u16* __restrict__ vf,
                                                 u16* __restrict__ aoh, u16* __restrict__ aol) {
  const int t = threadIdx.x;
  const int w = t >> 6;
  const int l = t & 63;
  const int lr = l & 15;
  const int lc = l >> 4;
  const int hh = blockIdx.y;
  const int n0 = blockIdx.x * 32;
  const int br = blockIdx.z;
  qb += (size_t)br * 2097152;
  kf += (size_t)br * 524288 + (size_t)hh * 65536;
  vf += (size_t)br * 524288 + (size_t)hh * 65536;
  aoh += (size_t)br * 4194304;
  aol += (size_t)br * 4194304;

  __shared__ __align__(16) u16 Pl[4][2304];   // per-wave P^T: [32 q][72 kv]
  __shared__ float Osum[4][64][33];           // per-wave O^T partial [d][q]
  __shared__ float Lsum[4][32];
  u16* Pw = &Pl[w][0];

  // Q^T B-fragments: [qh][khalf]
  short8 bq[2][2];
#pragma unroll
  for (int qh = 0; qh < 2; ++qh) {
    const size_t qrow = (size_t)(n0 + qh * 16 + lr) * 512 + hh * 64;
    bq[qh][0] = *(const short8*)&qb[qrow + lc * 8];
    bq[qh][1] = *(const short8*)&qb[qrow + 32 + lc * 8];
  }

  f32x4 acc[4][2];   // [db][qh]
#pragma unroll
  for (int a = 0; a < 4; ++a)
#pragma unroll
    for (int b = 0; b < 2; ++b) acc[a][b] = (f32x4){0.f, 0.f, 0.f, 0.f};
  float lsum0 = 0.f, lsum1 = 0.f;

  for (int it = 0; it < 4; ++it) {
    const int m0 = w * 256 + it * 64;

    // ---- issue all K and V frag loads for this tile (contiguous 1 KB each)
    const u16* ktile = kf + (size_t)(m0 >> 4) * 1024;
    const u16* vtile = vf + (size_t)(m0 >> 5) * 2048;
    short8 kc[8], av[8];
#pragma unroll
    for (int f = 0; f < 8; ++f)
      kc[f] = *(const short8*)&ktile[(size_t)f * 512 + l * 8];
#pragma unroll
    for (int f = 0; f < 8; ++f)
      av[f] = *(const short8*)&vtile[(size_t)f * 512 + l * 8];

    // ---- QK^T + softmax per kv-frag (keeps st lifetime short)
#pragma unroll
    for (int f = 0; f < 4; ++f) {
      f32x4 st0 = (f32x4){0.f, 0.f, 0.f, 0.f};
      f32x4 st1 = (f32x4){0.f, 0.f, 0.f, 0.f};
      __builtin_amdgcn_s_setprio(1);
      st0 = __builtin_amdgcn_mfma_f32_16x16x32_bf16(kc[f * 2 + 0], bq[0][0], st0, 0, 0, 0);
      st0 = __builtin_amdgcn_mfma_f32_16x16x32_bf16(kc[f * 2 + 1], bq[0][1], st0, 0, 0, 0);
      st1 = __builtin_amdgcn_mfma_f32_16x16x32_bf16(kc[f * 2 + 0], bq[1][0], st1, 0, 0, 0);
      st1 = __builtin_amdgcn_mfma_f32_16x16x32_bf16(kc[f * 2 + 1], bq[1][1], st1, 0, 0, 0);
      __builtin_amdgcn_s_setprio(0);
      float p0, p1, p2, p3;
      asm("v_exp_f32 %0, %1" : "=v"(p0) : "v"(st0[0]));
      asm("v_exp_f32 %0, %1" : "=v"(p1) : "v"(st0[1]));
      asm("v_exp_f32 %0, %1" : "=v"(p2) : "v"(st0[2]));
      asm("v_exp_f32 %0, %1" : "=v"(p3) : "v"(st0[3]));
      lsum0 += (p0 + p1) + (p2 + p3);
      u32 pa, pb;
      asm("v_cvt_pk_bf16_f32 %0, %1, %2" : "=v"(pa) : "v"(p0), "v"(p1));
      asm("v_cvt_pk_bf16_f32 %0, %1, %2" : "=v"(pb) : "v"(p2), "v"(p3));
      uint2 pk0; pk0.x = pa; pk0.y = pb;
      *(uint2*)&Pw[lr * 72 + f * 16 + lc * 4] = pk0;
      asm("v_exp_f32 %0, %1" : "=v"(p0) : "v"(st1[0]));
      asm("v_exp_f32 %0, %1" : "=v"(p1) : "v"(st1[1]));
      asm("v_exp_f32 %0, %1" : "=v"(p2) : "v"(st1[2]));
      asm("v_exp_f32 %0, %1" : "=v"(p3) : "v"(st1[3]));
      lsum1 += (p0 + p1) + (p2 + p3);
      asm("v_cvt_pk_bf16_f32 %0, %1, %2" : "=v"(pa) : "v"(p0), "v"(p1));
      asm("v_cvt_pk_bf16_f32 %0, %1, %2" : "=v"(pb) : "v"(p2), "v"(p3));
      uint2 pk1; pk1.x = pa; pk1.y = pb;
      *(uint2*)&Pw[(16 + lr) * 72 + f * 16 + lc * 4] = pk1;
    }

    // ---- PV: O^T += V^T . P^T
#pragma unroll
    for (int ks = 0; ks < 2; ++ks) {
#pragma unroll
      for (int qh = 0; qh < 2; ++qh) {
        short8 bp = *(const short8*)&Pw[(qh * 16 + lr) * 72 + ks * 32 + lc * 8];
        __builtin_amdgcn_s_setprio(1);
#pragma unroll
        for (int db = 0; db < 4; ++db)
          acc[db][qh] = __builtin_amdgcn_mfma_f32_16x16x32_bf16(av[ks * 4 + db], bp, acc[db][qh], 0, 0, 0);
        __builtin_amdgcn_s_setprio(0);
      }
    }
  }

  // ---- per-wave partial -> LDS
  lsum0 += __shfl_xor(lsum0, 16, 64);
  lsum0 += __shfl_xor(lsum0, 32, 64);
  lsum1 += __shfl_xor(lsum1, 16, 64);
  lsum1 += __shfl_xor(lsum1, 32, 64);
#pragma unroll
  for (int db = 0; db < 4; ++db)
#pragma unroll
    for (int qh = 0; qh < 2; ++qh)
#pragma unroll
      for (int j = 0; j < 4; ++j)
        Osum[w][db * 16 + lc * 4 + j][qh * 16 + lr] = acc[db][qh][j];
  if (lc == 0) { Lsum[w][lr] = lsum0; Lsum[w][16 + lr] = lsum1; }
  __syncthreads();

  // ---- combine 4 wave-partials, normalize, split-write
  const int q = t & 31;
  const int d0 = (t >> 5) * 8;
  const float linv = 1.0f / (Lsum[0][q] + Lsum[1][q] + Lsum[2][q] + Lsum[3][q]);
  short8 hv, lv;
#pragma unroll
  for (int i = 0; i < 8; ++i) {
    const int d = d0 + i;
    float v = (Osum[0][d][q] + Osum[1][d][q] + Osum[2][d][q] + Osum[3][d][q]) * linv;
    u16 hi = f2bf(v);
    hv[i] = (short)hi;
    lv[i] = (short)f2bf(v - bf2f(hi));
  }
  const size_t ob = (size_t)(n0 + q) * 512 + hh * 64 + d0;
  *(short8*)&aoh[ob] = hv;
  *(short8*)&aol[ob] = lv;
}

// ---------- token exchange ----------
__global__ __launch_bounds__(256) void exchange_f32(float* __restrict__ out,
                                                    const float* __restrict__ mask0,
                                                    const float* __restrict__ mask1) {
  int idx = blockIdx.x * 256 + threadIdx.x;
  int n = idx >> 9;
  float o0 = out[idx];
  float o1 = out[idx + NTOK * CDIM];
  bool k0 = mask0[n] >= 0.02f;
  bool k1 = mask1[n] >= 0.02f;
  out[idx] = k0 ? o0 : o1;
  out[idx + NTOK * CDIM] = k1 ? o1 : o0;
}

extern "C" void kernel_launch(void* const* d_in, const int* in_sizes, int n_in,
                              void* d_out, int out_size, void* d_ws, size_t ws_size,
                              hipStream_t stream) {
  const float* x0    = (const float*)d_in[0];
  const float* x1    = (const float*)d_in[1];
  const float* mask0 = (const float*)d_in[2];
  const float* mask1 = (const float*)d_in[3];
  const float* Wq    = (const float*)d_in[4];
  const float* Wkv   = (const float*)d_in[5];
  const float* Wsr   = (const float*)d_in[6];
  const float* bsr   = (const float*)d_in[7];
  const float* gamma = (const float*)d_in[8];
  const float* beta  = (const float*)d_in[9];
  const float* Wp    = (const float*)d_in[10];
  const float* bp    = (const float*)d_in[11];

  u16* U = (u16*)d_ws;
  size_t o = 0;
  u16* WqTh = U + o; o += 262144;  u16* WqTl = U + o; o += 262144;
  u16* WkvTh = U + o; o += 524288; u16* WkvTl = U + o; o += 524288;
  u16* WpTh = U + o; o += 262144;  u16* WpTl = U + o; o += 262144;
  u16* W2Th = U + o; o += 1048576; u16* W2Tl = U + o; o += 1048576;
  u16* x0h = U + o; o += 2097152;  u16* x0l = U + o; o += 2097152;
  u16* x1h = U + o; o += 2097152;  u16* x1l = U + o; o += 2097152;
  u16* qb2 = U + o; o += 4194304;
  u16* xnh = U + o; o += 1048576;
  u16* xnl = U + o; o += 1048576;
  u16* kvb = U + o; o += 2097152;
  u16* vt  = U + o; o += 1048576;   // (unused, layout stability)
  float* xr = (float*)(U + o);      // conv partials: 2 br x 2 parts x 524288 f32
  // kf/vf reuse the xr region (dead by the time kvpack runs)
  u16* kf = (u16*)xr;               // 2 br x 524288
  u16* vf = kf + 1048576;           // 2 br x 524288
  u16* aoh = x0h;   // branch stride 4194304 maps x0h->x1h, x0l->x1l
  u16* aol = x0l;

  float* out = (float*)d_out;
  dim3 blk(256);

  // weight prep
  tsplit<<<1024, blk, 0, stream>>>(Wq, WqTh, WqTl, 512);
  tsplit<<<2048, blk, 0, stream>>>(Wkv, WkvTh, WkvTl, 1024);
  tsplit<<<1024, blk, 0, stream>>>(Wp, WpTh, WpTl, 512);
  wsr_split<<<4096, blk, 0, stream>>>(Wsr, W2Th, W2Tl);

  // x splits
  fsplit<<<8192, blk, 0, stream>>>(x0, x0h, x0l);
  fsplit<<<8192, blk, 0, stream>>>(x1, x1h, x1l);

  // q projection -> bf16 q, pre-scaled by hd^-0.5 * log2(e)
  gemm_sp<<<dim3(8, 64, 2), blk, 0, stream>>>(x0h, x0l, x1h, x1l, WqTh, WqTl,
      4096, 512, 512, 512, 1, 2, nullptr, qb2, nullptr, nullptr, nullptr,
      0.125f * 1.4426950408889634f, 0);

  // SR conv as gather-GEMM, split-K=2 -> f32 partials
  gemm_sp<<<dim3(8, 16, 4), blk, 0, stream>>>(x0h, x0l, x1h, x1l, W2Th, W2Tl,
      1024, 512, 2048, 1024, 2, 0, xr, nullptr, nullptr, nullptr, nullptr, 1.0f, 1);

  // LayerNorm (+bsr) -> split bf16
  ln_split<<<dim3(1024, 2), blk, 0, stream>>>(xr, bsr, gamma, beta, xnh, xnl);

  // kv projection -> bf16 kv
  gemm_sp<<<dim3(16, 16, 2), blk, 0, stream>>>(xnh, xnl, xnh + 524288, xnl + 524288,
      WkvTh, WkvTl, 1024, 1024, 512, 512, 1, 2, nullptr, kvb, nullptr, nullptr, nullptr, 1.0f, 0);

  // pack K and V^T into MFMA fragment layout
  kvpack<<<1024, blk, 0, stream>>>(kvb, kf, vf);

  // attention -> ao hi/lo  (32 q per block, 4-way KV split, fragment loads)
  attn_mfma<<<dim3(128, 8, 2), blk, 0, stream>>>(qb2, kf, vf, aoh, aol);

  // output projection + bias + mask -> f32 out
  gemm_sp<<<dim3(8, 64, 2), blk, 0, stream>>>(aoh, aol, aoh + 4194304, aol + 4194304,
      WpTh, WpTl, 4096, 512, 512, 512, 1, 1, out, nullptr, bp, mask0, mask1, 1.0f, 0);

  // token exchange
  exchange_f32<<<8192, blk, 0, stream>>>(out, mask0, mask1);
}

// Round 7
// 186.378 us; speedup vs baseline: 1.6576x; 1.0866x over previous
//
#include <hip/hip_runtime.h>
#include <math.h>

typedef unsigned short u16;
typedef unsigned int u32;
typedef unsigned long long u64;
typedef __attribute__((ext_vector_type(8))) short short8;
typedef __attribute__((ext_vector_type(4))) float f32x4;

#define CDIM 512
#define NTOK 4096
#define MTOK 1024
#define NHEAD 8

// ---------- bf16 helpers ----------
__device__ __forceinline__ u16 f2bf(float x) {
  u32 b = __float_as_uint(x);
  u32 r = (b + 0x7FFFu + ((b >> 16) & 1u)) >> 16;
  return (u16)r;
}
__device__ __forceinline__ float bf2f(u16 u) {
  return __uint_as_float(((u32)u) << 16);
}

__device__ __forceinline__ void gload16(const void* g, void* l) {
  __builtin_amdgcn_global_load_lds(
      (const __attribute__((address_space(1))) u32*)g,
      (__attribute__((address_space(3))) u32*)l, 16, 0, 0);
}

// ---------- fused prep: weight transposes/splits + x splits ----------
// blocks [0,1024): WqT; [1024,3072): WkvT; [3072,4096): WpT;
// [4096,8192): W2T (Wsr); [8192,16384): x0 split; [16384,24576): x1 split.
__global__ __launch_bounds__(256) void prep_all(
    const float* __restrict__ Wq, const float* __restrict__ Wkv,
    const float* __restrict__ Wp, const float* __restrict__ Wsr,
    const float* __restrict__ x0, const float* __restrict__ x1,
    u16* __restrict__ WqTh, u16* __restrict__ WqTl,
    u16* __restrict__ WkvTh, u16* __restrict__ WkvTl,
    u16* __restrict__ WpTh, u16* __restrict__ WpTl,
    u16* __restrict__ W2Th, u16* __restrict__ W2Tl,
    u16* __restrict__ x0h, u16* __restrict__ x0l,
    u16* __restrict__ x1h, u16* __restrict__ x1l) {
  const int b = blockIdx.x;
  const int tt = threadIdx.x;
  float v; u16 hi;
  if (b < 1024) {
    int idx = b * 256 + tt;                 // 512*512, dst [n][k]
    int n = idx >> 9, k = idx & 511;
    v = Wq[(size_t)k * 512 + n];
    hi = f2bf(v); WqTh[idx] = hi; WqTl[idx] = f2bf(v - bf2f(hi));
  } else if (b < 3072) {
    int idx = (b - 1024) * 256 + tt;        // 1024*512
    int n = idx >> 9, k = idx & 511;
    v = Wkv[(size_t)k * 1024 + n];
    hi = f2bf(v); WkvTh[idx] = hi; WkvTl[idx] = f2bf(v - bf2f(hi));
  } else if (b < 4096) {
    int idx = (b - 3072) * 256 + tt;        // 512*512
    int n = idx >> 9, k = idx & 511;
    v = Wp[(size_t)k * 512 + n];
    hi = f2bf(v); WpTh[idx] = hi; WpTl[idx] = f2bf(v - bf2f(hi));
  } else if (b < 8192) {
    int idx = (b - 4096) * 256 + tt;        // 512*2048: [o][r], r=p*512+i
    int o = idx >> 11, r = idx & 2047;
    int p = r >> 9, i = r & 511;
    v = Wsr[(size_t)o * 2048 + i * 4 + p];
    hi = f2bf(v); W2Th[idx] = hi; W2Tl[idx] = f2bf(v - bf2f(hi));
  } else if (b < 16384) {
    int idx = (b - 8192) * 256 + tt;        // 4096*512
    v = x0[idx];
    hi = f2bf(v); x0h[idx] = hi; x0l[idx] = f2bf(v - bf2f(hi));
  } else {
    int idx = (b - 16384) * 256 + tt;
    v = x1[idx];
    hi = f2bf(v); x1h[idx] = hi; x1l[idx] = f2bf(v - bf2f(hi));
  }
}

// ---------- split-bf16 MFMA GEMM, 64x64 tile, 2-phase dbuf + XCD swizzle ----------
// A (per branch): [M][K] bf16 hi/lo (or gather from x for conv). BT: [N][K] hi/lo.
// modes: 0 = f32 at Of + bz*M*N; 1 = f32 (+bias)*mask at Of + br*M*N;
//        2 = bf16(acc*oscale) at Ob + br*M*N.
__global__ __launch_bounds__(256) void gemm_sp(
    const u16* __restrict__ A0h, const u16* __restrict__ A0l,
    const u16* __restrict__ A1h, const u16* __restrict__ A1l,
    const u16* __restrict__ BTh, const u16* __restrict__ BTl,
    int M, int N, int K, int kc, int nk, int mode,
    float* __restrict__ Of, u16* __restrict__ Ob,
    const float* __restrict__ bias,
    const float* __restrict__ mask0, const float* __restrict__ mask1,
    float oscale, int gather) {
  const int t = threadIdx.x;
  const int w = t >> 6;
  const int l = t & 63;
  const int lr = l & 15;
  const int lc = l >> 4;

  // bijective XCD-chunk swizzle (total blocks % 8 == 0 for all our grids)
  const int nwx = gridDim.x, nwy = gridDim.y;
  const int total = nwx * nwy * gridDim.z;
  const int L = blockIdx.x + nwx * (blockIdx.y + nwy * blockIdx.z);
  const int chunk = total >> 3;
  int W = (L & 7) * chunk + (L >> 3);
  const int wx = W % nwx; W /= nwx;
  const int wy = W % nwy;
  const int bz = W / nwy;

  const int br = bz / nk, kcid = bz % nk;
  const int row0 = wy * 64;
  const int col0 = wx * 64;
  const int koff = kcid * kc;
  const u16* Ah = br ? A1h : A0h;
  const u16* Al = br ? A1l : A0l;

  // double-buffered fragment-major tiles: [buf][4 frags x 512 u16]
  __shared__ u16 sAh[2][2048], sAl[2][2048], sBh[2][2048], sBl[2][2048];

  auto stage = [&](int buf, int k0) {
    const int ar = w * 16 + lr;
    size_t ga;
    if (gather) {
      const int k = k0 + lc * 8;
      const int p = k >> 9;
      const int ii = k & 511;
      const int m = row0 + ar;
      const int token = (((m >> 5) * 2 + (p >> 1)) << 6) + ((m & 31) * 2 + (p & 1));
      ga = (size_t)token * 512 + ii;
    } else {
      ga = (size_t)(row0 + ar) * K + k0 + lc * 8;
    }
    gload16(Ah + ga, (void*)&sAh[buf][w * 512]);
    gload16(Al + ga, (void*)&sAl[buf][w * 512]);
    const size_t gb = (size_t)(col0 + ar) * K + k0 + lc * 8;
    gload16(BTh + gb, (void*)&sBh[buf][w * 512]);
    gload16(BTl + gb, (void*)&sBl[buf][w * 512]);
  };

  f32x4 acc[2][2];
#pragma unroll
  for (int a = 0; a < 2; ++a)
#pragma unroll
    for (int b = 0; b < 2; ++b) acc[a][b] = (f32x4){0.f, 0.f, 0.f, 0.f};

  const int nt = kc >> 5;
  const int wr = (w >> 1) * 2;
  const int wc = (w & 1) * 2;

  // prologue: stage tile 0, wait
  stage(0, koff);
  __syncthreads();

  int cur = 0;
  for (int ti = 0; ti < nt; ++ti) {
    // issue next tile's loads into the other buffer (latency hides under compute)
    if (ti + 1 < nt) stage(cur ^ 1, koff + (ti + 1) * 32);

    short8 ah[2], al[2], bh[2], bl[2];
#pragma unroll
    for (int i = 0; i < 2; ++i) {
      ah[i] = *(const short8*)&sAh[cur][(wr + i) * 512 + l * 8];
      al[i] = *(const short8*)&sAl[cur][(wr + i) * 512 + l * 8];
      bh[i] = *(const short8*)&sBh[cur][(wc + i) * 512 + l * 8];
      bl[i] = *(const short8*)&sBl[cur][(wc + i) * 512 + l * 8];
    }
#pragma unroll
    for (int mt = 0; mt < 2; ++mt)
#pragma unroll
      for (int nt2 = 0; nt2 < 2; ++nt2) {
        acc[mt][nt2] = __builtin_amdgcn_mfma_f32_16x16x32_bf16(ah[mt], bh[nt2], acc[mt][nt2], 0, 0, 0);
        acc[mt][nt2] = __builtin_amdgcn_mfma_f32_16x16x32_bf16(ah[mt], bl[nt2], acc[mt][nt2], 0, 0, 0);
        acc[mt][nt2] = __builtin_amdgcn_mfma_f32_16x16x32_bf16(al[mt], bh[nt2], acc[mt][nt2], 0, 0, 0);
      }
    __syncthreads();   // drains this wave's vmcnt (next-tile stage) + orders buffers
    cur ^= 1;
  }

  const int rowb = row0 + (w >> 1) * 32;
  const int colb = col0 + (w & 1) * 32;
  const size_t obase = (mode == 0) ? (size_t)bz * M * N : (size_t)br * M * N;
#pragma unroll
  for (int mt = 0; mt < 2; ++mt)
#pragma unroll
    for (int nt2 = 0; nt2 < 2; ++nt2) {
      const int col = colb + nt2 * 16 + lr;
#pragma unroll
      for (int j = 0; j < 4; ++j) {
        const int row = rowb + mt * 16 + lc * 4 + j;
        float v = acc[mt][nt2][j];
        if (mode == 0) {
          Of[obase + (size_t)row * N + col] = v;
        } else if (mode == 1) {
          float mv = br ? mask1[row] : mask0[row];
          Of[obase + (size_t)row * N + col] = (v + bias[col]) * mv;
        } else {
          Ob[obase + (size_t)row * N + col] = f2bf(v * oscale);
        }
      }
    }
}

// ---------- LayerNorm: sum 2 conv partials + bsr, normalize, split to bf16 hi/lo ----------
__global__ __launch_bounds__(256) void ln_split(const float* __restrict__ xr,
                                                const float* __restrict__ bsr,
                                                const float* __restrict__ gamma,
                                                const float* __restrict__ beta,
                                                u16* __restrict__ xnh, u16* __restrict__ xnl) {
  const int row = blockIdx.x;
  const int br = blockIdx.y;
  const int t = threadIdx.x;
  const float* p = xr + (size_t)br * 2 * 524288 + (size_t)row * 512;
  const int c = t * 2;
  float v0 = p[c] + p[524288 + c] + bsr[c];
  float v1 = p[c + 1] + p[524288 + c + 1] + bsr[c + 1];
  float s = v0 + v1, sq = v0 * v0 + v1 * v1;
#pragma unroll
  for (int m = 1; m < 64; m <<= 1) {
    s += __shfl_xor(s, m, 64);
    sq += __shfl_xor(sq, m, 64);
  }
  __shared__ float ls[4], lsq[4];
  if ((t & 63) == 0) { ls[t >> 6] = s; lsq[t >> 6] = sq; }
  __syncthreads();
  s = ls[0] + ls[1] + ls[2] + ls[3];
  sq = lsq[0] + lsq[1] + lsq[2] + lsq[3];
  float mean = s * (1.0f / 512.0f);
  float var = sq * (1.0f / 512.0f) - mean * mean;
  float rs = rsqrtf(var + 1e-5f);
  size_t ob = (size_t)br * 524288 + (size_t)row * 512 + c;
  float y0 = (v0 - mean) * rs * gamma[c] + beta[c];
  float y1 = (v1 - mean) * rs * gamma[c + 1] + beta[c + 1];
  u16 h0 = f2bf(y0), h1 = f2bf(y1);
  xnh[ob] = h0; xnh[ob + 1] = h1;
  xnl[ob] = f2bf(y0 - bf2f(h0)); xnl[ob + 1] = f2bf(y1 - bf2f(h1));
}

// ---------- pack K and V^T into MFMA A-fragment layout ----------
__global__ __launch_bounds__(256) void kvpack(const u16* __restrict__ kvb,
                                              u16* __restrict__ kf, u16* __restrict__ vf) {
  const int tg = blockIdx.x * 256 + threadIdx.x;   // 2^18 threads
  const int l = tg & 63;
  const int frag = (tg >> 6) & 127;
  const int h = (tg >> 13) & 7;
  const int br = (tg >> 16) & 1;
  const int which = tg >> 17;
  const int lr = l & 15;
  const int lq = l >> 4;
  const size_t dst = (size_t)br * 524288 + (size_t)h * 65536 + (size_t)frag * 512 + l * 8;
  if (which == 0) {
    const int m = (frag >> 1) * 16 + lr;
    const int d = (frag & 1) * 32 + lq * 8;
    short8 v = *(const short8*)&kvb[(size_t)br * 1048576 + (size_t)m * 1024 + h * 64 + d];
    *(short8*)&kf[dst] = v;
  } else {
    const int m = (frag >> 2) * 32 + lq * 8;
    const int d = (frag & 3) * 16 + lr;
    const u16* src = &kvb[(size_t)br * 1048576 + (size_t)m * 1024 + 512 + h * 64 + d];
    short8 v;
#pragma unroll
    for (int j = 0; j < 8; ++j) v[j] = (short)src[(size_t)j * 1024];
    *(short8*)&vf[dst] = v;
  }
}

// ---------- MFMA flash attention: fragment K/V, 32 q per block, 4-way KV split ----------
__global__ __launch_bounds__(256) void attn_mfma(const u16* __restrict__ qb,
                                                 const u16* __restrict__ kf,
                                                 const u16* __restrict__ vf,
                                                 u16* __restrict__ aoh, u16* __restrict__ aol) {
  const int t = threadIdx.x;
  const int w = t >> 6;
  const int l = t & 63;
  const int lr = l & 15;
  const int lc = l >> 4;
  const int hh = blockIdx.y;
  const int n0 = blockIdx.x * 32;
  const int br = blockIdx.z;
  qb += (size_t)br * 2097152;
  kf += (size_t)br * 524288 + (size_t)hh * 65536;
  vf += (size_t)br * 524288 + (size_t)hh * 65536;
  aoh += (size_t)br * 4194304;
  aol += (size_t)br * 4194304;

  __shared__ __align__(16) u16 Pl[4][2304];   // per-wave P^T: [32 q][72 kv]
  __shared__ float Osum[4][64][33];           // per-wave O^T partial [d][q]
  __shared__ float Lsum[4][32];
  u16* Pw = &Pl[w][0];

  short8 bq[2][2];
#pragma unroll
  for (int qh = 0; qh < 2; ++qh) {
    const size_t qrow = (size_t)(n0 + qh * 16 + lr) * 512 + hh * 64;
    bq[qh][0] = *(const short8*)&qb[qrow + lc * 8];
    bq[qh][1] = *(const short8*)&qb[qrow + 32 + lc * 8];
  }

  f32x4 acc[4][2];   // [db][qh]
#pragma unroll
  for (int a = 0; a < 4; ++a)
#pragma unroll
    for (int b = 0; b < 2; ++b) acc[a][b] = (f32x4){0.f, 0.f, 0.f, 0.f};
  float lsum0 = 0.f, lsum1 = 0.f;

  for (int it = 0; it < 4; ++it) {
    const int m0 = w * 256 + it * 64;

    const u16* ktile = kf + (size_t)(m0 >> 4) * 1024;
    const u16* vtile = vf + (size_t)(m0 >> 5) * 2048;
    short8 kc[8], av[8];
#pragma unroll
    for (int f = 0; f < 8; ++f)
      kc[f] = *(const short8*)&ktile[(size_t)f * 512 + l * 8];
#pragma unroll
    for (int f = 0; f < 8; ++f)
      av[f] = *(const short8*)&vtile[(size_t)f * 512 + l * 8];

#pragma unroll
    for (int f = 0; f < 4; ++f) {
      f32x4 st0 = (f32x4){0.f, 0.f, 0.f, 0.f};
      f32x4 st1 = (f32x4){0.f, 0.f, 0.f, 0.f};
      __builtin_amdgcn_s_setprio(1);
      st0 = __builtin_amdgcn_mfma_f32_16x16x32_bf16(kc[f * 2 + 0], bq[0][0], st0, 0, 0, 0);
      st0 = __builtin_amdgcn_mfma_f32_16x16x32_bf16(kc[f * 2 + 1], bq[0][1], st0, 0, 0, 0);
      st1 = __builtin_amdgcn_mfma_f32_16x16x32_bf16(kc[f * 2 + 0], bq[1][0], st1, 0, 0, 0);
      st1 = __builtin_amdgcn_mfma_f32_16x16x32_bf16(kc[f * 2 + 1], bq[1][1], st1, 0, 0, 0);
      __builtin_amdgcn_s_setprio(0);
      float p0, p1, p2, p3;
      asm("v_exp_f32 %0, %1" : "=v"(p0) : "v"(st0[0]));
      asm("v_exp_f32 %0, %1" : "=v"(p1) : "v"(st0[1]));
      asm("v_exp_f32 %0, %1" : "=v"(p2) : "v"(st0[2]));
      asm("v_exp_f32 %0, %1" : "=v"(p3) : "v"(st0[3]));
      lsum0 += (p0 + p1) + (p2 + p3);
      u32 pa, pb;
      asm("v_cvt_pk_bf16_f32 %0, %1, %2" : "=v"(pa) : "v"(p0), "v"(p1));
      asm("v_cvt_pk_bf16_f32 %0, %1, %2" : "=v"(pb) : "v"(p2), "v"(p3));
      uint2 pk0; pk0.x = pa; pk0.y = pb;
      *(uint2*)&Pw[lr * 72 + f * 16 + lc * 4] = pk0;
      asm("v_exp_f32 %0, %1" : "=v"(p0) : "v"(st1[0]));
      asm("v_exp_f32 %0, %1" : "=v"(p1) : "v"(st1[1]));
      asm("v_exp_f32 %0, %1" : "=v"(p2) : "v"(st1[2]));
      asm("v_exp_f32 %0, %1" : "=v"(p3) : "v"(st1[3]));
      lsum1 += (p0 + p1) + (p2 + p3);
      asm("v_cvt_pk_bf16_f32 %0, %1, %2" : "=v"(pa) : "v"(p0), "v"(p1));
      asm("v_cvt_pk_bf16_f32 %0, %1, %2" : "=v"(pb) : "v"(p2), "v"(p3));
      uint2 pk1; pk1.x = pa; pk1.y = pb;
      *(uint2*)&Pw[(16 + lr) * 72 + f * 16 + lc * 4] = pk1;
    }

#pragma unroll
    for (int ks = 0; ks < 2; ++ks) {
#pragma unroll
      for (int qh = 0; qh < 2; ++qh) {
        short8 bp = *(const short8*)&Pw[(qh * 16 + lr) * 72 + ks * 32 + lc * 8];
        __builtin_amdgcn_s_setprio(1);
#pragma unroll
        for (int db = 0; db < 4; ++db)
          acc[db][qh] = __builtin_amdgcn_mfma_f32_16x16x32_bf16(av[ks * 4 + db], bp, acc[db][qh], 0, 0, 0);
        __builtin_amdgcn_s_setprio(0);
      }
    }
  }

  lsum0 += __shfl_xor(lsum0, 16, 64);
  lsum0 += __shfl_xor(lsum0, 32, 64);
  lsum1 += __shfl_xor(lsum1, 16, 64);
  lsum1 += __shfl_xor(lsum1, 32, 64);
#pragma unroll
  for (int db = 0; db < 4; ++db)
#pragma unroll
    for (int qh = 0; qh < 2; ++qh)
#pragma unroll
      for (int j = 0; j < 4; ++j)
        Osum[w][db * 16 + lc * 4 + j][qh * 16 + lr] = acc[db][qh][j];
  if (lc == 0) { Lsum[w][lr] = lsum0; Lsum[w][16 + lr] = lsum1; }
  __syncthreads();

  const int q = t & 31;
  const int d0 = (t >> 5) * 8;
  const float linv = 1.0f / (Lsum[0][q] + Lsum[1][q] + Lsum[2][q] + Lsum[3][q]);
  short8 hv, lv;
#pragma unroll
  for (int i = 0; i < 8; ++i) {
    const int d = d0 + i;
    float v = (Osum[0][d][q] + Osum[1][d][q] + Osum[2][d][q] + Osum[3][d][q]) * linv;
    u16 hi = f2bf(v);
    hv[i] = (short)hi;
    lv[i] = (short)f2bf(v - bf2f(hi));
  }
  const size_t ob = (size_t)(n0 + q) * 512 + hh * 64 + d0;
  *(short8*)&aoh[ob] = hv;
  *(short8*)&aol[ob] = lv;
}

// ---------- token exchange ----------
__global__ __launch_bounds__(256) void exchange_f32(float* __restrict__ out,
                                                    const float* __restrict__ mask0,
                                                    const float* __restrict__ mask1) {
  int idx = blockIdx.x * 256 + threadIdx.x;
  int n = idx >> 9;
  float o0 = out[idx];
  float o1 = out[idx + NTOK * CDIM];
  bool k0 = mask0[n] >= 0.02f;
  bool k1 = mask1[n] >= 0.02f;
  out[idx] = k0 ? o0 : o1;
  out[idx + NTOK * CDIM] = k1 ? o1 : o0;
}

extern "C" void kernel_launch(void* const* d_in, const int* in_sizes, int n_in,
                              void* d_out, int out_size, void* d_ws, size_t ws_size,
                              hipStream_t stream) {
  const float* x0    = (const float*)d_in[0];
  const float* x1    = (const float*)d_in[1];
  const float* mask0 = (const float*)d_in[2];
  const float* mask1 = (const float*)d_in[3];
  const float* Wq    = (const float*)d_in[4];
  const float* Wkv   = (const float*)d_in[5];
  const float* Wsr   = (const float*)d_in[6];
  const float* bsr   = (const float*)d_in[7];
  const float* gamma = (const float*)d_in[8];
  const float* beta  = (const float*)d_in[9];
  const float* Wp    = (const float*)d_in[10];
  const float* bp    = (const float*)d_in[11];

  u16* U = (u16*)d_ws;
  size_t o = 0;
  u16* WqTh = U + o; o += 262144;  u16* WqTl = U + o; o += 262144;
  u16* WkvTh = U + o; o += 524288; u16* WkvTl = U + o; o += 524288;
  u16* WpTh = U + o; o += 262144;  u16* WpTl = U + o; o += 262144;
  u16* W2Th = U + o; o += 1048576; u16* W2Tl = U + o; o += 1048576;
  u16* x0h = U + o; o += 2097152;  u16* x0l = U + o; o += 2097152;
  u16* x1h = U + o; o += 2097152;  u16* x1l = U + o; o += 2097152;
  u16* qb2 = U + o; o += 4194304;
  u16* xnh = U + o; o += 1048576;
  u16* xnl = U + o; o += 1048576;
  u16* kvb = U + o; o += 2097152;
  float* xr = (float*)(U + o);      // conv partials: 2 br x 2 parts x 524288 f32
  // kf/vf reuse the xr region (dead after ln_split)
  u16* kf = (u16*)xr;               // 2 br x 524288
  u16* vf = kf + 1048576;           // 2 br x 524288
  u16* aoh = x0h;   // branch stride 4194304 maps x0h->x1h, x0l->x1l
  u16* aol = x0l;

  float* out = (float*)d_out;
  dim3 blk(256);

  // fused prep (weights + x splits)
  prep_all<<<24576, blk, 0, stream>>>(Wq, Wkv, Wp, Wsr, x0, x1,
      WqTh, WqTl, WkvTh, WkvTl, WpTh, WpTl, W2Th, W2Tl, x0h, x0l, x1h, x1l);

  // q projection -> bf16 q, pre-scaled by hd^-0.5 * log2(e)
  gemm_sp<<<dim3(8, 64, 2), blk, 0, stream>>>(x0h, x0l, x1h, x1l, WqTh, WqTl,
      4096, 512, 512, 512, 1, 2, nullptr, qb2, nullptr, nullptr, nullptr,
      0.125f * 1.4426950408889634f, 0);

  // SR conv as gather-GEMM, split-K=2 -> f32 partials
  gemm_sp<<<dim3(8, 16, 4), blk, 0, stream>>>(x0h, x0l, x1h, x1l, W2Th, W2Tl,
      1024, 512, 2048, 1024, 2, 0, xr, nullptr, nullptr, nullptr, nullptr, 1.0f, 1);

  // LayerNorm (+bsr) -> split bf16
  ln_split<<<dim3(1024, 2), blk, 0, stream>>>(xr, bsr, gamma, beta, xnh, xnl);

  // kv projection -> bf16 kv
  gemm_sp<<<dim3(16, 16, 2), blk, 0, stream>>>(xnh, xnl, xnh + 524288, xnl + 524288,
      WkvTh, WkvTl, 1024, 1024, 512, 512, 1, 2, nullptr, kvb, nullptr, nullptr, nullptr, 1.0f, 0);

  // pack K and V^T into MFMA fragment layout
  kvpack<<<1024, blk, 0, stream>>>(kvb, kf, vf);

  // attention -> ao hi/lo  (32 q per block, 4-way KV split, fragment loads)
  attn_mfma<<<dim3(128, 8, 2), blk, 0, stream>>>(qb2, kf, vf, aoh, aol);

  // output projection + bias + mask -> f32 out
  gemm_sp<<<dim3(8, 64, 2), blk, 0, stream>>>(aoh, aol, aoh + 4194304, aol + 4194304,
      WpTh, WpTl, 4096, 512, 512, 512, 1, 1, out, nullptr, bp, mask0, mask1, 1.0f, 0);

  // token exchange
  exchange_f32<<<8192, blk, 0, stream>>>(out, mask0, mask1);
}

// Round 8
// 138.174 us; speedup vs baseline: 2.2359x; 1.3489x over previous
//
#include <hip/hip_runtime.h>
#include <math.h>

typedef unsigned short u16;
typedef unsigned int u32;
typedef unsigned long long u64;
typedef __attribute__((ext_vector_type(8))) short short8;
typedef __attribute__((ext_vector_type(4))) float f32x4;

#define CDIM 512
#define NTOK 4096
#define MTOK 1024
#define NHEAD 8

// ---------- bf16 helpers ----------
__device__ __forceinline__ u16 f2bf(float x) {
  u32 b = __float_as_uint(x);
  u32 r = (b + 0x7FFFu + ((b >> 16) & 1u)) >> 16;
  return (u16)r;
}
__device__ __forceinline__ float bf2f(u16 u) {
  return __uint_as_float(((u32)u) << 16);
}

__device__ __forceinline__ void gload16(const void* g, void* l) {
  __builtin_amdgcn_global_load_lds(
      (const __attribute__((address_space(1))) u32*)g,
      (__attribute__((address_space(3))) u32*)l, 16, 0, 0);
}

// ==================== fragment-packing prep ====================
// Frag layout (1024 B each): packed[frag*512 + l*8 + j] =
//   Mat[mt*16 + (l&15)][kt*32 + (l>>4)*8 + j],  frag = mt*Kf + kt.
// Blocks: [0,128) WqT; [128,384) WkvT; [384,512) WpT; [512,1024) W2T;
//         [1024,3072) xq (q-proj A); [3072,5120) xc (conv gather A).
__global__ __launch_bounds__(256) void prep_pack(
    const float* __restrict__ Wq, const float* __restrict__ Wkv,
    const float* __restrict__ Wp, const float* __restrict__ Wsr,
    const float* __restrict__ x0, const float* __restrict__ x1,
    u16* __restrict__ WqTph, u16* __restrict__ WqTpl,
    u16* __restrict__ WkvTph, u16* __restrict__ WkvTpl,
    u16* __restrict__ WpTph, u16* __restrict__ WpTpl,
    u16* __restrict__ W2Tph, u16* __restrict__ W2Tpl,
    u16* __restrict__ xqh, u16* __restrict__ xql,
    u16* __restrict__ xch, u16* __restrict__ xcl) {
  const int b = blockIdx.x, t = threadIdx.x;
  const int fid = t >> 6, l = t & 63, lr = l & 15, lc = l >> 4;
  float v[8];
  u16* dh; u16* dl; size_t dst;
  if (b < 512) {
    const float* W; u16 *oh, *ol; int N, f;
    if (b < 128)      { W = Wq;  oh = WqTph;  ol = WqTpl;  N = 512;  f = b * 4 + fid; }
    else if (b < 384) { W = Wkv; oh = WkvTph; ol = WkvTpl; N = 1024; f = (b - 128) * 4 + fid; }
    else              { W = Wp;  oh = WpTph;  ol = WpTpl;  N = 512;  f = (b - 384) * 4 + fid; }
    const int nt = f >> 4, kt = f & 15;
    const int n = nt * 16 + lr, k0 = kt * 32 + lc * 8;
#pragma unroll
    for (int j = 0; j < 8; ++j) v[j] = W[(size_t)(k0 + j) * N + n];
    dh = oh; dl = ol; dst = (size_t)f * 512 + l * 8;
  } else if (b < 1024) {
    const int f = (b - 512) * 4 + fid;          // ot*64 + kt (2048 frags)
    const int ot = f >> 6, kt = f & 63;
    const int o = ot * 16 + lr;
    const int r0 = kt * 32 + lc * 8;
    const int p = r0 >> 9, i0 = r0 & 511;
#pragma unroll
    for (int j = 0; j < 8; ++j) v[j] = Wsr[(size_t)o * 2048 + (size_t)(i0 + j) * 4 + p];
    dh = W2Tph; dl = W2Tpl; dst = (size_t)f * 512 + l * 8;
  } else if (b < 3072) {
    const int g = (b - 1024) * 4 + fid;         // br(2) x mt(256) x kt(16)
    const int br = g >> 12, fl = g & 4095;
    const int mt = fl >> 4, kt = fl & 15;
    const float* x = br ? x1 : x0;
    const float* src = x + (size_t)(mt * 16 + lr) * 512 + kt * 32 + lc * 8;
#pragma unroll
    for (int j = 0; j < 8; ++j) v[j] = src[j];
    dh = xqh; dl = xql; dst = (size_t)br * 2097152 + (size_t)fl * 512 + l * 8;
  } else {
    const int g = (b - 3072) * 4 + fid;         // br(2) x mt(64) x kt(64)
    const int br = g >> 12, fl = g & 4095;
    const int mt = fl >> 6, kt = fl & 63;
    const int m = mt * 16 + lr;
    const int p = kt >> 4, i0 = (kt * 32 + lc * 8) & 511;
    const int token = (((m >> 5) * 2 + (p >> 1)) << 6) + ((m & 31) * 2 + (p & 1));
    const float* x = br ? x1 : x0;
    const float* src = x + (size_t)token * 512 + i0;
#pragma unroll
    for (int j = 0; j < 8; ++j) v[j] = src[j];
    dh = xch; dl = xcl; dst = (size_t)br * 2097152 + (size_t)fl * 512 + l * 8;
  }
  short8 hv, lv;
#pragma unroll
  for (int j = 0; j < 8; ++j) {
    u16 hi = f2bf(v[j]);
    hv[j] = (short)hi;
    lv[j] = (short)f2bf(v[j] - bf2f(hi));
  }
  *(short8*)&dh[dst] = hv;
  *(short8*)&dl[dst] = lv;
}

// ==================== split-bf16 MFMA GEMM (frag-packed inputs) ====================
// A/B: frag-packed, Kf frags per row-frag. ktiles K-steps starting at kcid*ktiles.
// modes: 0 = f32 at Of + bz*M*N; 1 = f32 (+bias)*mask at Of + br*M*N;
//        2 = bf16(acc*oscale) row-major at Ob + br*M*N.
__global__ __launch_bounds__(256) void gemm_sp(
    const u16* __restrict__ A0h, const u16* __restrict__ A0l,
    const u16* __restrict__ A1h, const u16* __restrict__ A1l,
    const u16* __restrict__ BTh, const u16* __restrict__ BTl,
    int M, int N, int Kf, int ktiles, int nk, int mode,
    float* __restrict__ Of, u16* __restrict__ Ob,
    const float* __restrict__ bias,
    const float* __restrict__ mask0, const float* __restrict__ mask1,
    float oscale) {
  const int t = threadIdx.x;
  const int w = t >> 6;
  const int l = t & 63;
  const int lr = l & 15;
  const int lc = l >> 4;

  // bijective XCD-chunk swizzle (all grids have total % 8 == 0)
  const int nwx = gridDim.x, nwy = gridDim.y;
  const int total = nwx * nwy * gridDim.z;
  const int L = blockIdx.x + nwx * (blockIdx.y + nwy * blockIdx.z);
  const int chunk = total >> 3;
  int W = (L & 7) * chunk + (L >> 3);
  const int wx = W % nwx; W /= nwx;
  const int wy = W % nwy;
  const int bz = W / nwy;

  const int br = bz / nk, kcid = bz % nk;
  const int row0 = wy * 64;
  const int col0 = wx * 64;
  const u16* Ah = br ? A1h : A0h;
  const u16* Al = br ? A1l : A0l;

  const size_t abase = (size_t)((row0 >> 4) + w) * Kf * 512 + (size_t)l * 8;
  const size_t bbase = (size_t)((col0 >> 4) + w) * Kf * 512 + (size_t)l * 8;

  __shared__ u16 sAh[2][2048], sAl[2][2048], sBh[2][2048], sBl[2][2048];

  auto stage = [&](int buf, int kt) {
    gload16(Ah + abase + (size_t)kt * 512, (void*)&sAh[buf][w * 512]);
    gload16(Al + abase + (size_t)kt * 512, (void*)&sAl[buf][w * 512]);
    gload16(BTh + bbase + (size_t)kt * 512, (void*)&sBh[buf][w * 512]);
    gload16(BTl + bbase + (size_t)kt * 512, (void*)&sBl[buf][w * 512]);
  };

  f32x4 acc[2][2];
#pragma unroll
  for (int a = 0; a < 2; ++a)
#pragma unroll
    for (int b2 = 0; b2 < 2; ++b2) acc[a][b2] = (f32x4){0.f, 0.f, 0.f, 0.f};

  const int kt0 = kcid * ktiles;
  const int wr = (w >> 1) * 2;
  const int wc = (w & 1) * 2;

  stage(0, kt0);
  __syncthreads();

  int cur = 0;
  for (int ti = 0; ti < ktiles; ++ti) {
    if (ti + 1 < ktiles) stage(cur ^ 1, kt0 + ti + 1);

    short8 ah[2], al[2], bh[2], bl[2];
#pragma unroll
    for (int i = 0; i < 2; ++i) {
      ah[i] = *(const short8*)&sAh[cur][(wr + i) * 512 + l * 8];
      al[i] = *(const short8*)&sAl[cur][(wr + i) * 512 + l * 8];
      bh[i] = *(const short8*)&sBh[cur][(wc + i) * 512 + l * 8];
      bl[i] = *(const short8*)&sBl[cur][(wc + i) * 512 + l * 8];
    }
#pragma unroll
    for (int mt = 0; mt < 2; ++mt)
#pragma unroll
      for (int nt2 = 0; nt2 < 2; ++nt2) {
        acc[mt][nt2] = __builtin_amdgcn_mfma_f32_16x16x32_bf16(ah[mt], bh[nt2], acc[mt][nt2], 0, 0, 0);
        acc[mt][nt2] = __builtin_amdgcn_mfma_f32_16x16x32_bf16(ah[mt], bl[nt2], acc[mt][nt2], 0, 0, 0);
        acc[mt][nt2] = __builtin_amdgcn_mfma_f32_16x16x32_bf16(al[mt], bh[nt2], acc[mt][nt2], 0, 0, 0);
      }
    __syncthreads();
    cur ^= 1;
  }

  const int rowb = row0 + (w >> 1) * 32;
  const int colb = col0 + (w & 1) * 32;
  const size_t obase = (mode == 0) ? (size_t)bz * M * N : (size_t)br * M * N;
#pragma unroll
  for (int mt = 0; mt < 2; ++mt)
#pragma unroll
    for (int nt2 = 0; nt2 < 2; ++nt2) {
      const int col = colb + nt2 * 16 + lr;
#pragma unroll
      for (int j = 0; j < 4; ++j) {
        const int row = rowb + mt * 16 + lc * 4 + j;
        float v = acc[mt][nt2][j];
        if (mode == 0) {
          Of[obase + (size_t)row * N + col] = v;
        } else if (mode == 1) {
          float mv = br ? mask1[row] : mask0[row];
          Of[obase + (size_t)row * N + col] = (v + bias[col]) * mv;
        } else {
          Ob[obase + (size_t)row * N + col] = f2bf(v * oscale);
        }
      }
    }
}

// ==================== LayerNorm -> frag-packed bf16 hi/lo ====================
__global__ __launch_bounds__(256) void ln_split(const float* __restrict__ xr,
                                                const float* __restrict__ bsr,
                                                const float* __restrict__ gamma,
                                                const float* __restrict__ beta,
                                                u16* __restrict__ xnph, u16* __restrict__ xnpl) {
  const int row = blockIdx.x;
  const int br = blockIdx.y;
  const int t = threadIdx.x;
  const float* p = xr + (size_t)br * 2 * 524288 + (size_t)row * 512;
  const int c = t * 2;
  float v0 = p[c] + p[524288 + c] + bsr[c];
  float v1 = p[c + 1] + p[524288 + c + 1] + bsr[c + 1];
  float s = v0 + v1, sq = v0 * v0 + v1 * v1;
#pragma unroll
  for (int m = 1; m < 64; m <<= 1) {
    s += __shfl_xor(s, m, 64);
    sq += __shfl_xor(sq, m, 64);
  }
  __shared__ float ls[4], lsq[4];
  __shared__ float ybuf[512];
  if ((t & 63) == 0) { ls[t >> 6] = s; lsq[t >> 6] = sq; }
  __syncthreads();
  s = ls[0] + ls[1] + ls[2] + ls[3];
  sq = lsq[0] + lsq[1] + lsq[2] + lsq[3];
  float mean = s * (1.0f / 512.0f);
  float var = sq * (1.0f / 512.0f) - mean * mean;
  float rs = rsqrtf(var + 1e-5f);
  ybuf[c] = (v0 - mean) * rs * gamma[c] + beta[c];
  ybuf[c + 1] = (v1 - mean) * rs * gamma[c + 1] + beta[c + 1];
  __syncthreads();
  if (t < 128) {
    const int which = t >> 6, ch = t & 63;
    const int c0 = ch * 8;
    const int kt = c0 >> 5, lcf = (c0 >> 3) & 3, lrf = row & 15;
    const size_t dst = (size_t)br * 524288 +
        ((size_t)(row >> 4) * 16 + kt) * 512 + (lcf * 16 + lrf) * 8;
    short8 o8;
    if (which == 0) {
#pragma unroll
      for (int j = 0; j < 8; ++j) o8[j] = (short)f2bf(ybuf[c0 + j]);
      *(short8*)&xnph[dst] = o8;
    } else {
#pragma unroll
      for (int j = 0; j < 8; ++j) {
        float v = ybuf[c0 + j];
        o8[j] = (short)f2bf(v - bf2f(f2bf(v)));
      }
      *(short8*)&xnpl[dst] = o8;
    }
  }
}

// ==================== pack K and V^T into MFMA A-fragment layout ====================
__global__ __launch_bounds__(256) void kvpack(const u16* __restrict__ kvb,
                                              u16* __restrict__ kf, u16* __restrict__ vf) {
  const int tg = blockIdx.x * 256 + threadIdx.x;   // 2^18 threads
  const int l = tg & 63;
  const int frag = (tg >> 6) & 127;
  const int h = (tg >> 13) & 7;
  const int br = (tg >> 16) & 1;
  const int which = tg >> 17;
  const int lr = l & 15;
  const int lq = l >> 4;
  const size_t dst = (size_t)br * 524288 + (size_t)h * 65536 + (size_t)frag * 512 + l * 8;
  if (which == 0) {
    const int m = (frag >> 1) * 16 + lr;
    const int d = (frag & 1) * 32 + lq * 8;
    short8 v = *(const short8*)&kvb[(size_t)br * 1048576 + (size_t)m * 1024 + h * 64 + d];
    *(short8*)&kf[dst] = v;
  } else {
    const int m = (frag >> 2) * 32 + lq * 8;
    const int d = (frag & 3) * 16 + lr;
    const u16* src = &kvb[(size_t)br * 1048576 + (size_t)m * 1024 + 512 + h * 64 + d];
    short8 v;
#pragma unroll
    for (int j = 0; j < 8; ++j) v[j] = (short)src[(size_t)j * 1024];
    *(short8*)&vf[dst] = v;
  }
}

// ==================== MFMA flash attention (32 q/block, 4-way KV split) ====================
// Output written FRAG-PACKED for the out-proj GEMM (branch stride 2097152).
__global__ __launch_bounds__(256) void attn_mfma(const u16* __restrict__ qb,
                                                 const u16* __restrict__ kf,
                                                 const u16* __restrict__ vf,
                                                 u16* __restrict__ aoph, u16* __restrict__ aopl) {
  const int t = threadIdx.x;
  const int w = t >> 6;
  const int l = t & 63;
  const int lr = l & 15;
  const int lc = l >> 4;
  const int hh = blockIdx.y;
  const int n0 = blockIdx.x * 32;
  const int br = blockIdx.z;
  qb += (size_t)br * 2097152;
  kf += (size_t)br * 524288 + (size_t)hh * 65536;
  vf += (size_t)br * 524288 + (size_t)hh * 65536;
  aoph += (size_t)br * 2097152;
  aopl += (size_t)br * 2097152;

  __shared__ __align__(16) u16 Pl[4][2304];   // per-wave P^T: [32 q][72 kv]
  __shared__ float Osum[4][64][33];           // per-wave O^T partial [d][q]
  __shared__ float Lsum[4][32];
  u16* Pw = &Pl[w][0];

  short8 bq[2][2];
#pragma unroll
  for (int qh = 0; qh < 2; ++qh) {
    const size_t qrow = (size_t)(n0 + qh * 16 + lr) * 512 + hh * 64;
    bq[qh][0] = *(const short8*)&qb[qrow + lc * 8];
    bq[qh][1] = *(const short8*)&qb[qrow + 32 + lc * 8];
  }

  f32x4 acc[4][2];   // [db][qh]
#pragma unroll
  for (int a = 0; a < 4; ++a)
#pragma unroll
    for (int b = 0; b < 2; ++b) acc[a][b] = (f32x4){0.f, 0.f, 0.f, 0.f};
  float lsum0 = 0.f, lsum1 = 0.f;

  for (int it = 0; it < 4; ++it) {
    const int m0 = w * 256 + it * 64;

    const u16* ktile = kf + (size_t)(m0 >> 4) * 1024;
    const u16* vtile = vf + (size_t)(m0 >> 5) * 2048;
    short8 kc[8], av[8];
#pragma unroll
    for (int f = 0; f < 8; ++f)
      kc[f] = *(const short8*)&ktile[(size_t)f * 512 + l * 8];
#pragma unroll
    for (int f = 0; f < 8; ++f)
      av[f] = *(const short8*)&vtile[(size_t)f * 512 + l * 8];

#pragma unroll
    for (int f = 0; f < 4; ++f) {
      f32x4 st0 = (f32x4){0.f, 0.f, 0.f, 0.f};
      f32x4 st1 = (f32x4){0.f, 0.f, 0.f, 0.f};
      __builtin_amdgcn_s_setprio(1);
      st0 = __builtin_amdgcn_mfma_f32_16x16x32_bf16(kc[f * 2 + 0], bq[0][0], st0, 0, 0, 0);
      st0 = __builtin_amdgcn_mfma_f32_16x16x32_bf16(kc[f * 2 + 1], bq[0][1], st0, 0, 0, 0);
      st1 = __builtin_amdgcn_mfma_f32_16x16x32_bf16(kc[f * 2 + 0], bq[1][0], st1, 0, 0, 0);
      st1 = __builtin_amdgcn_mfma_f32_16x16x32_bf16(kc[f * 2 + 1], bq[1][1], st1, 0, 0, 0);
      __builtin_amdgcn_s_setprio(0);
      float p0, p1, p2, p3;
      asm("v_exp_f32 %0, %1" : "=v"(p0) : "v"(st0[0]));
      asm("v_exp_f32 %0, %1" : "=v"(p1) : "v"(st0[1]));
      asm("v_exp_f32 %0, %1" : "=v"(p2) : "v"(st0[2]));
      asm("v_exp_f32 %0, %1" : "=v"(p3) : "v"(st0[3]));
      lsum0 += (p0 + p1) + (p2 + p3);
      u32 pa, pb;
      asm("v_cvt_pk_bf16_f32 %0, %1, %2" : "=v"(pa) : "v"(p0), "v"(p1));
      asm("v_cvt_pk_bf16_f32 %0, %1, %2" : "=v"(pb) : "v"(p2), "v"(p3));
      uint2 pk0; pk0.x = pa; pk0.y = pb;
      *(uint2*)&Pw[lr * 72 + f * 16 + lc * 4] = pk0;
      asm("v_exp_f32 %0, %1" : "=v"(p0) : "v"(st1[0]));
      asm("v_exp_f32 %0, %1" : "=v"(p1) : "v"(st1[1]));
      asm("v_exp_f32 %0, %1" : "=v"(p2) : "v"(st1[2]));
      asm("v_exp_f32 %0, %1" : "=v"(p3) : "v"(st1[3]));
      lsum1 += (p0 + p1) + (p2 + p3);
      asm("v_cvt_pk_bf16_f32 %0, %1, %2" : "=v"(pa) : "v"(p0), "v"(p1));
      asm("v_cvt_pk_bf16_f32 %0, %1, %2" : "=v"(pb) : "v"(p2), "v"(p3));
      uint2 pk1; pk1.x = pa; pk1.y = pb;
      *(uint2*)&Pw[(16 + lr) * 72 + f * 16 + lc * 4] = pk1;
    }

#pragma unroll
    for (int ks = 0; ks < 2; ++ks) {
#pragma unroll
      for (int qh = 0; qh < 2; ++qh) {
        short8 bp = *(const short8*)&Pw[(qh * 16 + lr) * 72 + ks * 32 + lc * 8];
        __builtin_amdgcn_s_setprio(1);
#pragma unroll
        for (int db = 0; db < 4; ++db)
          acc[db][qh] = __builtin_amdgcn_mfma_f32_16x16x32_bf16(av[ks * 4 + db], bp, acc[db][qh], 0, 0, 0);
        __builtin_amdgcn_s_setprio(0);
      }
    }
  }

  lsum0 += __shfl_xor(lsum0, 16, 64);
  lsum0 += __shfl_xor(lsum0, 32, 64);
  lsum1 += __shfl_xor(lsum1, 16, 64);
  lsum1 += __shfl_xor(lsum1, 32, 64);
#pragma unroll
  for (int db = 0; db < 4; ++db)
#pragma unroll
    for (int qh = 0; qh < 2; ++qh)
#pragma unroll
      for (int j = 0; j < 4; ++j)
        Osum[w][db * 16 + lc * 4 + j][qh * 16 + lr] = acc[db][qh][j];
  if (lc == 0) { Lsum[w][lr] = lsum0; Lsum[w][16 + lr] = lsum1; }
  __syncthreads();

  // combine wave partials, normalize, write FRAG-PACKED hi/lo
  const int q = t & 31;
  const int d0 = (t >> 5) * 8;
  const float linv = 1.0f / (Lsum[0][q] + Lsum[1][q] + Lsum[2][q] + Lsum[3][q]);
  short8 hv, lv;
#pragma unroll
  for (int i = 0; i < 8; ++i) {
    const int d = d0 + i;
    float v = (Osum[0][d][q] + Osum[1][d][q] + Osum[2][d][q] + Osum[3][d][q]) * linv;
    u16 hi = f2bf(v);
    hv[i] = (short)hi;
    lv[i] = (short)f2bf(v - bf2f(hi));
  }
  const int mrow = n0 + q;
  const int kcoord = hh * 64 + d0;
  const size_t dst = ((size_t)(mrow >> 4) * 16 + (kcoord >> 5)) * 512 +
                     (((kcoord >> 3) & 3) * 16 + (mrow & 15)) * 8;
  *(short8*)&aoph[dst] = hv;
  *(short8*)&aopl[dst] = lv;
}

// ==================== token exchange ====================
__global__ __launch_bounds__(256) void exchange_f32(float* __restrict__ out,
                                                    const float* __restrict__ mask0,
                                                    const float* __restrict__ mask1) {
  int idx = blockIdx.x * 256 + threadIdx.x;
  int n = idx >> 9;
  float o0 = out[idx];
  float o1 = out[idx + NTOK * CDIM];
  bool k0 = mask0[n] >= 0.02f;
  bool k1 = mask1[n] >= 0.02f;
  out[idx] = k0 ? o0 : o1;
  out[idx + NTOK * CDIM] = k1 ? o1 : o0;
}

extern "C" void kernel_launch(void* const* d_in, const int* in_sizes, int n_in,
                              void* d_out, int out_size, void* d_ws, size_t ws_size,
                              hipStream_t stream) {
  const float* x0    = (const float*)d_in[0];
  const float* x1    = (const float*)d_in[1];
  const float* mask0 = (const float*)d_in[2];
  const float* mask1 = (const float*)d_in[3];
  const float* Wq    = (const float*)d_in[4];
  const float* Wkv   = (const float*)d_in[5];
  const float* Wsr   = (const float*)d_in[6];
  const float* bsr   = (const float*)d_in[7];
  const float* gamma = (const float*)d_in[8];
  const float* beta  = (const float*)d_in[9];
  const float* Wp    = (const float*)d_in[10];
  const float* bp    = (const float*)d_in[11];

  u16* U = (u16*)d_ws;
  u16* WqTph  = U;                    // 262144
  u16* WqTpl  = WqTph + 262144;
  u16* WkvTph = WqTpl + 262144;       // 524288
  u16* WkvTpl = WkvTph + 524288;
  u16* WpTph  = WkvTpl + 524288;      // 262144
  u16* WpTpl  = WpTph + 262144;
  u16* W2Tph  = WpTpl + 262144;       // 1048576
  u16* W2Tpl  = W2Tph + 1048576;
  u16* xqh    = W2Tpl + 1048576;      // 4194304 (2 br, stride 2097152)
  u16* xql    = xqh + 4194304;
  u16* XC     = xql + 4194304;        // 8388608 region
  u16* xch    = XC;                   // 4194304 (2 br)
  u16* xcl    = XC + 4194304;
  // aliases into XC after conv consumes xc:
  u16* qb2    = XC;                   // 4194304
  u16* kvb    = XC + 4194304;         // 2097152
  u16* xnph   = XC + 6291456;         // 1048576 (2 br, stride 524288)
  u16* xnpl   = XC + 7340032;         // 1048576
  float* xr   = (float*)(XC + 8388608);  // 2097152 f32 (2 br x 2 parts)
  u16* kf     = (u16*)xr;             // alias after ln: 1048576
  u16* vf     = kf + 1048576;         // 1048576
  // aop aliases xq after q-proj:
  u16* aoph   = xqh;                  // 2 br, stride 2097152
  u16* aopl   = xql;

  float* out = (float*)d_out;
  dim3 blk(256);

  // fragment-packing prep (weights + x in q-proj and conv-gather orders)
  prep_pack<<<5120, blk, 0, stream>>>(Wq, Wkv, Wp, Wsr, x0, x1,
      WqTph, WqTpl, WkvTph, WkvTpl, WpTph, WpTpl, W2Tph, W2Tpl,
      xqh, xql, xch, xcl);

  // SR conv as packed GEMM, split-K=2 -> f32 partials (runs first: frees xc)
  gemm_sp<<<dim3(8, 16, 4), blk, 0, stream>>>(xch, xcl, xch + 2097152, xcl + 2097152,
      W2Tph, W2Tpl, 1024, 512, 64, 32, 2, 0, xr, nullptr, nullptr, nullptr, nullptr, 1.0f);

  // LayerNorm (+bsr) -> frag-packed bf16
  ln_split<<<dim3(1024, 2), blk, 0, stream>>>(xr, bsr, gamma, beta, xnph, xnpl);

  // q projection -> bf16 q row-major, pre-scaled by hd^-0.5 * log2(e)
  gemm_sp<<<dim3(8, 64, 2), blk, 0, stream>>>(xqh, xql, xqh + 2097152, xql + 2097152,
      WqTph, WqTpl, 4096, 512, 16, 16, 1, 2, nullptr, qb2, nullptr, nullptr, nullptr,
      0.125f * 1.4426950408889634f);

  // kv projection -> bf16 kv row-major
  gemm_sp<<<dim3(16, 16, 2), blk, 0, stream>>>(xnph, xnpl, xnph + 524288, xnpl + 524288,
      WkvTph, WkvTpl, 1024, 1024, 16, 16, 1, 2, nullptr, kvb, nullptr, nullptr, nullptr, 1.0f);

  // pack K and V^T into MFMA fragment layout
  kvpack<<<1024, blk, 0, stream>>>(kvb, kf, vf);

  // attention -> ao frag-packed hi/lo
  attn_mfma<<<dim3(128, 8, 2), blk, 0, stream>>>(qb2, kf, vf, aoph, aopl);

  // output projection + bias + mask -> f32 out
  gemm_sp<<<dim3(8, 64, 2), blk, 0, stream>>>(aoph, aopl, aoph + 2097152, aopl + 2097152,
      WpTph, WpTpl, 4096, 512, 16, 16, 1, 1, out, nullptr, bp, mask0, mask1, 1.0f);

  // token exchange
  exchange_f32<<<8192, blk, 0, stream>>>(out, mask0, mask1);
}